// Round 4
// baseline (1296.937 us; speedup 1.0000x reference)
//
#include <hip/hip_runtime.h>
#include <hip/hip_bf16.h>
#include <stdint.h>

// ---------------------------------------------------------------------------
// UnionBoxesAndFeats pipeline (R6):
//  k_setup   : per-pair union-roi sample coords + rect coverage vectors
//  k_prepw1  : W1 fp32 -> bf16 [128 o][128 k], k = c*64 + dy*8 + dx (padded)
//  k_fmapt   : fmap (C,H,W) -> (H*W, C), LDS-tiled transpose (both coalesced)
//  k_conv1   : per-pair MFMA GEMM (as R2)
//  k_stats1  : reduce partials -> a1,c1 (bn1 affine)
//  k_prepb2  : W2s = a1*W2 (bf16), T2t[pos][o] = b2 + pad-aware bn1-shift term
//  k_conv2   : implicit GEMM M=200704,N=256,K=1152 — R6: ZERO-LDS main loop.
//              All operands are L2-resident (FETCH 34.5MB vs 1.35GB logical),
//              and MFMA fragments (16 rows x 64B) gather from global at the
//              minimum 16 segments/instruction — LDS staging was pure
//              overhead (Common-mistake #7). Waves run barrier-free; af
//              ping-pong prefetch (1 step ahead), bb[] reloaded in-place
//              after last use. LDS only for the epilogue transpose.
//  k_stats2  : reduce -> a2,c2
//  k_final   : out = RoIAlign(union roi) + a2*z+ + c2
// ---------------------------------------------------------------------------

typedef __attribute__((ext_vector_type(8))) short bf16x8;
typedef __attribute__((ext_vector_type(4))) float f32x4;
typedef __attribute__((ext_vector_type(2))) unsigned short u16x2;

__device__ __forceinline__ uint16_t f2b(float f) {          // fp32 -> bf16 RNE
  uint32_t x = __float_as_uint(f);
  return (uint16_t)((x + 0x7fffu + ((x >> 16) & 1u)) >> 16);
}
__device__ __forceinline__ float b2f(uint16_t u) {
  return __uint_as_float(((uint32_t)u) << 16);
}
__device__ __forceinline__ uint32_t pk2(float a, float b) { // packed RNE pair
  __hip_bfloat162 h = __float22bfloat162_rn(make_float2(a, b));
  union { __hip_bfloat162 h; uint32_t u; } cvt; cvt.h = h; return cvt.u;
}
__device__ __forceinline__ f32x4 mfma16(bf16x8 a, bf16x8 b, f32x4 c) {
  return __builtin_amdgcn_mfma_f32_16x16x32_bf16(a, b, c, 0, 0, 0);
}

#define NPAIR 4096

// ---------------------------------------------------------------- k_setup ---
__global__ void k_setup(const float* __restrict__ rois, const int* __restrict__ ui,
                        float* __restrict__ paird, float* __restrict__ zp)
{
  int p = blockIdx.x * 256 + threadIdx.x;
  if (blockIdx.x == 0 && threadIdx.x < 64) zp[threadIdx.x] = 0.f;  // zero page
  if (p >= NPAIR) return;
  int i0 = ui[2*p+0], i1 = ui[2*p+1];
  const float* r0 = rois + i0*5;
  const float* r1 = rois + i1*5;
  float ax1=r0[1], ay1=r0[2], ax2=r0[3], ay2=r0[4];
  float bx1=r1[1], by1=r1[2], bx2=r1[3], by2=r1[4];
  float ux1=fminf(ax1,bx1), uy1=fminf(ay1,by1);
  float ux2=fmaxf(ax2,bx2), uy2=fmaxf(ay2,by2);
  float* pd = paird + (size_t)p*136;
  const float sc = 1.0f/16.0f;
  #pragma unroll
  for (int j=0;j<7;j++){
    float t = (float)j * (1.0f/6.0f);
    float xs = ux1*sc*(1.0f-t) + ux2*sc*t;
    xs = fminf(fmaxf(xs, 0.0f), 36.0f);
    float xf = floorf(xs);
    pd[j] = xf; pd[7+j] = xs - xf;
    float ys = uy1*sc*(1.0f-t) + uy2*sc*t;
    ys = fminf(fmaxf(ys, 0.0f), 36.0f);
    float yf = floorf(ys);
    pd[14+j] = yf; pd[21+j] = ys - yf;
  }
  float w = ux2-ux1, h = uy2-uy1;
  float x1a[2] = {ax1,bx1}, x2a[2] = {ax2,bx2};
  float y1a[2] = {ay1,by1}, y2a[2] = {ay2,by2};
  #pragma unroll
  for (int k=0;k<2;k++){
    float sx1 = (x1a[k]-ux1)/w*27.0f;
    float sx2 = (x2a[k]-ux1)/w*27.0f;
    float sy1 = (y1a[k]-uy1)/h*27.0f;
    float sy2 = (y2a[k]-uy1)/h*27.0f;
    for (int g=0; g<27; g++){
      float gg = (float)g;
      float cx = fminf(fmaxf(fminf(gg+1.0f, sx2) - fmaxf(gg, sx1), 0.0f), 1.0f);
      float cy = fminf(fmaxf(fminf(gg+1.0f, sy2) - fmaxf(gg, sy1), 0.0f), 1.0f);
      pd[28 + k*27 + g] = cx;   // cx ch0@28, ch1@55
      pd[82 + k*27 + g] = cy;   // cy ch0@82, ch1@109
    }
  }
}

// --------------------------------------------------------------- k_prepw1 ---
// W1b[o][k], k = cch*64 + dy*8 + dx  (dy,dx in 0..6 real, slot 7 zero)
__global__ void k_prepw1(const float* __restrict__ W1, uint16_t* __restrict__ W1b)
{
  int idx = blockIdx.x*256 + threadIdx.x;   // 64 blocks -> 16384
  int o = idx >> 7, kk = idx & 127;
  int cch = kk >> 6, r = kk & 63, dy = r >> 3, dx = r & 7;
  float v = (dy < 7 && dx < 7) ? W1[o*98 + cch*49 + dy*7 + dx] : 0.f;
  W1b[idx] = f2b(v);
}

// ---------------------------------------------------------------- k_fmapt ---
// tiled transpose: 64 (yx) x 64 (o) tiles; grid (22, 4)
__global__ void k_fmapt(const float* __restrict__ fmap, float* __restrict__ fmt){
  __shared__ float tile[64][65];
  int yx0 = blockIdx.x * 64;
  int o0  = blockIdx.y * 64;
  int tx = threadIdx.x & 63, ty = threadIdx.x >> 6;
  #pragma unroll
  for (int i=0;i<16;i++){
    int oo = ty*16 + i;
    int yx = yx0 + tx;
    tile[oo][tx] = (yx < 1369) ? fmap[(size_t)(o0+oo)*1369 + yx] : 0.f;
  }
  __syncthreads();
  #pragma unroll
  for (int i=0;i<16;i++){
    int r = ty*16 + i;
    int yx = yx0 + r;
    if (yx < 1369) fmt[(size_t)yx*256 + o0 + tx] = tile[tx][r];
  }
}

// ---------------------------------------------------------------- k_conv1 ---
// one block per pair, 512 threads. GEMM (o=128) x (m=256 pad, 196 real) x
// (k=128 pad, 98 real), operand-swapped: D rows = o, cols = m.
__global__ __launch_bounds__(512, 4) void k_conv1(
    const float* __restrict__ paird, const uint16_t* __restrict__ W1b,
    const float* __restrict__ b1v,
    uint16_t* __restrict__ p1, float* __restrict__ part1)
{
  __shared__ __align__(128) char lds[62976];
  uint16_t* smA  = (uint16_t*)lds;              // [256 m][72] per-64k chunk
  uint16_t* smB  = (uint16_t*)(lds + 36864);    // [128 o][72]
  uint16_t* smY  = (uint16_t*)lds;              // [196 m][132 o] epilogue (overlaps)
  float* cy0a = (float*)(lds + 55296);          // [14][8]
  float* cy1a = (float*)(lds + 55808);
  float* bya  = (float*)(lds + 56320);
  float* cx0a = (float*)(lds + 56832);
  float* cx1a = (float*)(lds + 57344);
  float* nbxa = (float*)(lds + 57856);
  float* smB1 = (float*)(lds + 58368);          // [128]
  float* smStat = (float*)(lds + 58880);        // [128][8]
  const int tid = threadIdx.x;
  const int n = blockIdx.x;
  const int wv = tid >> 6, lane = tid & 63, quad = lane >> 4, l15 = lane & 15;
  const float* pd = paird + (size_t)n*136;

  // phase 0: coverage lookup tables (slot dy/dx==7 -> 0)
  if (tid < 112){
    int Y = tid >> 3, dy = tid & 7;
    int yq = 2*Y + dy - 3;
    bool iy = (dy < 7) && ((unsigned)yq < 27u);
    int yqc = iy ? yq : 0;
    cy0a[tid] = iy ? pd[82+yqc]  : 0.f;
    cy1a[tid] = iy ? pd[109+yqc] : 0.f;
    bya[tid]  = iy ? 1.f : 0.f;
  } else if (tid >= 128 && tid < 240){
    int t2 = tid - 128;
    int X = t2 >> 3, dx = t2 & 7;
    int xq = 2*X + dx - 3;
    bool ix = (dx < 7) && ((unsigned)xq < 27u);
    int xqc = ix ? xq : 0;
    cx0a[t2] = ix ? pd[28+xqc] : 0.f;
    cx1a[t2] = ix ? pd[55+xqc] : 0.f;
    nbxa[t2] = ix ? -0.5f : 0.f;
  } else if (tid >= 256 && tid < 384){
    smB1[tid-256] = b1v[tid-256];
  }
  __syncthreads();

  const int m = tid & 255, h = tid >> 8;        // thread -> (A row, k-half)
  int Yr = m / 14, Xr = m - (m/14)*14;
  bool mv = (m < 196);
  int Yc = mv ? Yr : 0, Xc = mv ? Xr : 0;
  float byr[4], nbr[8];
  #pragma unroll
  for (int j=0;j<4;j++) byr[j] = mv ? bya[Yc*8 + h*4 + j] : 0.f;
  #pragma unroll
  for (int d=0;d<8;d++) nbr[d] = mv ? nbxa[Xc*8 + d] : 0.f;

  f32x4 zero4 = {0.f,0.f,0.f,0.f};
  f32x4 acc[8][2];
  #pragma unroll
  for (int io=0;io<8;io++){ acc[io][0] = zero4; acc[io][1] = zero4; }

  #pragma unroll
  for (int c=0;c<2;c++){
    // stage B chunk (bf16, already padded/ordered)
    {
      int o = tid >> 2, part = tid & 3;
      const uint4* src = (const uint4*)(W1b + o*128 + c*64);
      uint4* dst = (uint4*)(smB + o*72);
      dst[part*2]   = src[part*2];
      dst[part*2+1] = src[part*2+1];
    }
    // generate A chunk: k-local = dy*8+dx; per g, dy = h*4+g fixed
    {
      const float* cya = c ? cy1a : cy0a;
      const float* cxa = c ? cx1a : cx0a;
      float cyr[4], cxr[8];
      #pragma unroll
      for (int j=0;j<4;j++) cyr[j] = mv ? cya[Yc*8 + h*4 + j] : 0.f;
      #pragma unroll
      for (int d=0;d<8;d++) cxr[d] = mv ? cxa[Xc*8 + d] : 0.f;
      uint16_t* rowp = smA + m*72 + h*32;
      #pragma unroll
      for (int g=0; g<4; g++){
        uint32_t w[4];
        #pragma unroll
        for (int q=0; q<4; q++){
          float v0 = fmaf(cyr[g], cxr[q*2],   byr[g]*nbr[q*2]);
          float v1 = fmaf(cyr[g], cxr[q*2+1], byr[g]*nbr[q*2+1]);
          w[q] = pk2(v0, v1);
        }
        *(uint4*)(rowp + g*8) = make_uint4(w[0],w[1],w[2],w[3]);
      }
    }
    __syncthreads();
    #pragma unroll
    for (int ks=0; ks<2; ks++){
      bf16x8 rf0 = *(const bf16x8*)(smA + (wv*32      + l15)*72 + ks*32 + quad*8);
      bf16x8 rf1 = *(const bf16x8*)(smA + (wv*32 + 16 + l15)*72 + ks*32 + quad*8);
      #pragma unroll
      for (int io=0;io<8;io++){
        bf16x8 wf = *(const bf16x8*)(smB + (io*16 + l15)*72 + ks*32 + quad*8);
        acc[io][0] = mfma16(wf, rf0, acc[io][0]);
        acc[io][1] = mfma16(wf, rf1, acc[io][1]);
      }
    }
    __syncthreads();
  }

  // epilogue: y[m][o] = relu(acc + b1) -> smY, packed b64 writes
  #pragma unroll
  for (int io=0;io<8;io++){
    f32x4 bs = *(const f32x4*)(smB1 + io*16 + quad*4);
    #pragma unroll
    for (int jm=0;jm<2;jm++){
      int mm = wv*32 + jm*16 + l15;
      if (mm < 196){
        float v0 = fmaxf(acc[io][jm][0] + bs[0], 0.f);
        float v1 = fmaxf(acc[io][jm][1] + bs[1], 0.f);
        float v2 = fmaxf(acc[io][jm][2] + bs[2], 0.f);
        float v3 = fmaxf(acc[io][jm][3] + bs[3], 0.f);
        uint32_t w0 = pk2(v0,v1) & 0x7fff7fffu;   // clear -0 signs (u16 max safe)
        uint32_t w1 = pk2(v2,v3) & 0x7fff7fffu;
        *(uint2*)(smY + mm*132 + io*16 + quad*4) = make_uint2(w0, w1);
      }
    }
  }
  __syncthreads();

  // per-channel stats partials over 196 positions
  {
    int o = tid & 127, hh = tid >> 7;           // hh in 0..3, 49 rows each
    float S = 0.f, Q = 0.f;
    for (int r = hh*49; r < hh*49 + 49; r++){
      float v = b2f(smY[r*132 + o]);
      S += v; Q += v*v;
    }
    smStat[o*8 + hh*2 + 0] = S;
    smStat[o*8 + hh*2 + 1] = Q;
  }

  // maxpool 3x3 s2 of raw relu via packed u16 integer max (values >= 0)
  #pragma unroll
  for (int it=0; it<7; it++){
    int idx = tid + it*512;
    if (idx < 3136){
      int pos = idx >> 6, op2 = idx & 63;
      int Yp = pos / 7, Xp = pos - Yp*7;
      int yb = 2*Yp - 1, xb = 2*Xp - 1;
      u16x2 mx; mx.x = 0; mx.y = 0;
      #pragma unroll
      for (int a=0;a<3;a++){
        int yy = yb + a;
        if ((unsigned)yy < 14u){
          #pragma unroll
          for (int b=0;b<3;b++){
            int xx = xb + b;
            if ((unsigned)xx < 14u){
              u16x2 v = *(const u16x2*)(smY + (yy*14+xx)*132 + op2*2);
#if defined(__has_builtin) && __has_builtin(__builtin_elementwise_max)
              mx = __builtin_elementwise_max(mx, v);
#else
              mx.x = mx.x > v.x ? mx.x : v.x;
              mx.y = mx.y > v.y ? mx.y : v.y;
#endif
            }
          }
        }
      }
      *(uint32_t*)(p1 + ((size_t)n*49 + pos)*128 + op2*2) = *(uint32_t*)&mx;
    }
  }
  __syncthreads();
  if (tid < 128){
    float S = smStat[tid*8+0] + smStat[tid*8+2] + smStat[tid*8+4] + smStat[tid*8+6];
    float Q = smStat[tid*8+1] + smStat[tid*8+3] + smStat[tid*8+5] + smStat[tid*8+7];
    part1[((size_t)n*128 + tid)*2 + 0] = S;
    part1[((size_t)n*128 + tid)*2 + 1] = Q;
  }
}

// --------------------------------------------------------------- k_stats1 ---
__global__ void k_stats1(const float* __restrict__ part1, const float* __restrict__ g1,
                         const float* __restrict__ be1, float* __restrict__ ab1)
{
  __shared__ float sS[256], sQ[256];
  int ch = blockIdx.x, t = threadIdx.x;
  float S=0.f, Q=0.f;
  for (int i=t; i<4096; i+=256){
    S += part1[((size_t)i*128 + ch)*2 + 0];
    Q += part1[((size_t)i*128 + ch)*2 + 1];
  }
  sS[t]=S; sQ[t]=Q;
  __syncthreads();
  for (int s=128; s>0; s>>=1){
    if (t < s){ sS[t]+=sS[t+s]; sQ[t]+=sQ[t+s]; }
    __syncthreads();
  }
  if (t==0){
    float N = 4096.0f*196.0f;
    float mean = sS[0]/N;
    float var = sQ[0]/N - mean*mean;
    float a = g1[ch] * rsqrtf(var + 1e-5f);
    ab1[ch*2+0] = a;
    ab1[ch*2+1] = be1[ch] - mean*a;
  }
}

// --------------------------------------------------------------- k_prepb2 ---
__global__ void k_prepb2(const float* __restrict__ W2, const float* __restrict__ b2v,
                         const float* __restrict__ ab1,
                         uint16_t* __restrict__ W2s, uint16_t* __restrict__ T2t)
{
  __shared__ float sA[128], sC[128], sU[9];
  int o = blockIdx.x, t = threadIdx.x;
  if (t < 128){ sA[t] = ab1[t*2+0]; sC[t] = ab1[t*2+1]; }
  __syncthreads();
  const float* w = W2 + (size_t)o*1152;
  for (int k=t; k<1152; k+=256){
    int c = k & 127, tap = k >> 7;
    W2s[(size_t)o*1152 + k] = f2b(w[c*9 + tap] * sA[c]);
  }
  if (t < 9){
    float u = 0.f;
    for (int c=0;c<128;c++) u += sC[c] * w[c*9 + t];
    sU[t] = u;
  }
  __syncthreads();
  if (t < 49){
    int y = t / 7, x = t - (t/7)*7;
    float s = b2v[o];
    #pragma unroll
    for (int dy=0;dy<3;dy++)
      #pragma unroll
      for (int dx=0;dx<3;dx++){
        int yy = y+dy-1, xx = x+dx-1;
        if ((unsigned)yy < 7u && (unsigned)xx < 7u) s += sU[dy*3+dx];
      }
    T2t[t*256 + o] = f2b(s);
  }
}

// ---------------------------------------------------------------- k_conv2 ---
// implicit GEMM: M=200704 (tile 128), N=256, K=1152 in 36 steps of BK=32.
// R6: ZERO-LDS main loop — fragments gathered from global (L2-resident).
// A frag (ia): rows m0+wm*64+ia*16+l15, bytes p1[r*256 + tapdelta + ks*64
//  + quad*16 .. +16); invalid taps -> zero page (per-lane 9-bit mask).
// B frag (jb): o = wn*128+jb*16+l15, bytes W2s[o*2304 + s*64 + quad*16].
// Each load = 16 x 64B segments (minimum for 1KB) — LDS adds nothing.
// Pipeline per wave (no barriers): afA/afB ping-pong loaded 1 step ahead;
// bb[jb] reloaded in place right after its 4 MFMAs (28 MFMAs before reuse).
__global__ __launch_bounds__(256, 2) void k_conv2(
    const uint16_t* __restrict__ p1, const uint16_t* __restrict__ W2s,
    const uint16_t* __restrict__ T2t, const float* __restrict__ zpf,
    uint16_t* __restrict__ zplus, float* __restrict__ part2)
{
  __shared__ __align__(128) char lds[41472];   // epilogue only: smZ 16K @0, smT @16384
  const int tid = threadIdx.x;
  // XCD-bijective swizzle: 1568 % 8 == 0 -> contiguous 196-tile chunk per XCD
  const int bid = blockIdx.x;
  const int swz = (bid & 7) * 196 + (bid >> 3);
  const int m0 = swz * 128;
  const int wv = tid >> 6, lane = tid & 63, quad = lane >> 4, l15 = lane & 15;
  const int wm = wv >> 1, wn = wv & 1;
  const int qo = quad * 16;

  const char* p1c = (const char*)p1;
  const char* w2c = (const char*)W2s;
  const char* zpc = (const char*)zpf;

  // per-lane A row bases + 9-bit tap validity masks
  int aoff[4]; unsigned amask[4];
  #pragma unroll
  for (int ia=0; ia<4; ia++){
    int r = m0 + wm*64 + ia*16 + l15;
    aoff[ia] = (r << 8) + qo;
    int nn = r / 49, pp = r - nn*49, yy = pp/7, xx = pp - yy*7;
    unsigned mk = 0;
    #pragma unroll
    for (int dy=0; dy<3; dy++)
      #pragma unroll
      for (int dx=0; dx<3; dx++){
        int y2 = yy + dy - 1, x2 = xx + dx - 1;
        if ((unsigned)y2 < 7u && (unsigned)x2 < 7u) mk |= 1u << (dy*3+dx);
      }
    amask[ia] = mk;
  }
  // per-lane B bases
  int boff[8];
  #pragma unroll
  for (int jb=0;jb<8;jb++){
    int o = wn*128 + jb*16 + l15;
    boff[jb] = o*2304 + qo;
  }

  f32x4 zero4 = {0.f,0.f,0.f,0.f};
  f32x4 acc[4][8];
  #pragma unroll
  for (int ia=0;ia<4;ia++)
    #pragma unroll
    for (int jb=0;jb<8;jb++) acc[ia][jb] = zero4;

  bf16x8 afA[4], afB[4], bb[8];

  // tap t -> tapdelta (uniform): dy=t/3, dx=t%3 without div
  auto tdelta = [](int t)->int {
    int dy = (t >= 6) ? 2 : ((t >= 3) ? 1 : 0);
    int dx = t - dy*3;
    return ((dy-1)*7 + (dx-1)) << 8;
  };
  // per-lane A source pointers for a tap (zero page for invalid taps)
  auto selA = [&](const char** pA, int t, int tdel){
    unsigned bit = 1u << t;
    #pragma unroll
    for (int ia=0; ia<4; ia++)
      pA[ia] = (amask[ia] & bit) ? (p1c + (aoff[ia] + tdel)) : (zpc + qo);
  };
  auto loadA = [&](bf16x8* dst, const char* const* pA, int kso){
    #pragma unroll
    for (int ia=0; ia<4; ia++)
      dst[ia] = *(const bf16x8*)(pA[ia] + kso);
  };
  // 32 MFMAs consuming AF + bb; reload bb[jb] for next step after last use
  auto fstep = [&](const bf16x8* AF, const char* wnx, int kso, bool doB){
    __builtin_amdgcn_s_setprio(1);
    #pragma unroll
    for (int jb=0; jb<8; jb++){
      #pragma unroll
      for (int ia=0; ia<4; ia++)
        acc[ia][jb] = mfma16(AF[ia], bb[jb], acc[ia][jb]);
      if (doB) bb[jb] = *(const bf16x8*)(wnx + boff[jb] + kso);
    }
    __builtin_amdgcn_s_setprio(0);
  };

  // prologue: load (0,0) into afA + bb
  {
    const char* pA0[4];
    selA(pA0, 0, tdelta(0));
    loadA(afA, pA0, 0);
    #pragma unroll
    for (int jb=0; jb<8; jb++)
      bb[jb] = *(const bf16x8*)(w2c + boff[jb]);
  }

  for (int t=0; t<9; t++){
    int tdel = tdelta(t);
    const char* pAc[4];
    selA(pAc, t, tdel);
    const char* wt = w2c + t*256;
    // steps 4t+0 .. 4t+3 (consume set; prefetch next step's A; bb in-place)
    loadA(afB, pAc, 64);   fstep(afA, wt, 64, true);     // s=4t   -> next (t,1)
    loadA(afA, pAc, 128);  fstep(afB, wt, 128, true);    // s=4t+1 -> next (t,2)
    loadA(afB, pAc, 192);  fstep(afA, wt, 192, true);    // s=4t+2 -> next (t,3)
    if (t < 8){
      const char* pAn[4];
      selA(pAn, t+1, tdelta(t+1));
      loadA(afA, pAn, 0);  fstep(afB, wt + 256, 0, true); // s=4t+3 -> (t+1,0)
    } else {
      fstep(afB, w2c, 0, false);                          // s=35, no prefetch
    }
  }

  // ---- epilogue: bias+relu -> bf16, transpose via LDS in 4 quarters of 32 m
  uint16_t* smT = (uint16_t*)(lds + 16384);     // [49][256] bias table (24.5KB)
  #pragma unroll
  for (int i=0;i<7;i++){
    int ch = tid + i*256;
    if (ch < 1568) ((uint4*)smT)[ch] = ((const uint4*)T2t)[ch];
  }
  uint16_t* smZ = (uint16_t*)lds;               // [32][256] quarter buffer
  float S = 0.f, Q = 0.f;
  #pragma unroll
  for (int q=0; q<4; q++){
    __syncthreads();
    if (wm == (q>>1)){
      #pragma unroll
      for (int t2=0;t2<2;t2++){
        int ia = ((q&1)<<1) + t2;
        #pragma unroll
        for (int reg=0; reg<4; reg++){
          int rl = t2*16 + quad*4 + reg;        // row within quarter
          int mm = m0 + q*32 + rl;
          int pos = mm % 49;
          const uint16_t* tr = smT + pos*256 + wn*128;
          uint16_t* zr = smZ + rl*256 + wn*128;
          #pragma unroll
          for (int jb=0;jb<8;jb++){
            int col = jb*16 + l15;
            float z = acc[ia][jb][reg] + b2f(tr[col]);
            zr[col] = f2b(fmaxf(z, 0.0f));
          }
        }
      }
    }
    __syncthreads();
    #pragma unroll
    for (int i2=0;i2<4;i2++){
      int idx = tid + i2*256;                   // 1024 uint4 = 16KB
      int row = idx >> 5, off = idx & 31;
      *(uint4*)(zplus + ((size_t)(m0 + q*32 + row))*256 + off*8) = ((const uint4*)smZ)[idx];
    }
    for (int r=0;r<32;r++){
      float v = b2f(smZ[r*256 + tid]);
      S += v; Q += v*v;
    }
  }
  part2[((size_t)swz*256 + tid)*2 + 0] = S;
  part2[((size_t)swz*256 + tid)*2 + 1] = Q;
}

// --------------------------------------------------------------- k_stats2 ---
__global__ void k_stats2(const float* __restrict__ part2, const float* __restrict__ g2,
                         const float* __restrict__ be2, float* __restrict__ ab2)
{
  __shared__ float sS[256], sQ[256];
  int ch = blockIdx.x, t = threadIdx.x;
  float S=0.f, Q=0.f;
  for (int i=t; i<1568; i+=256){
    S += part2[((size_t)i*256 + ch)*2 + 0];
    Q += part2[((size_t)i*256 + ch)*2 + 1];
  }
  sS[t]=S; sQ[t]=Q;
  __syncthreads();
  for (int s=128; s>0; s>>=1){
    if (t < s){ sS[t]+=sS[t+s]; sQ[t]+=sQ[t+s]; }
    __syncthreads();
  }
  if (t==0){
    float N = 200704.0f;
    float mean = sS[0]/N;
    float var = sQ[0]/N - mean*mean;
    float a = g2[ch] * rsqrtf(var + 1e-5f);
    ab2[ch*2+0] = a;
    ab2[ch*2+1] = be2[ch] - mean*a;
  }
}

// ---------------------------------------------------------------- k_final ---
__global__ __launch_bounds__(256) void k_final(
    const float* __restrict__ paird, const float* __restrict__ fmt,
    const uint16_t* __restrict__ zplus, const float* __restrict__ ab2,
    float* __restrict__ out)
{
  __shared__ float smRes[12544];     // [o][pos] transpose buffer
  __shared__ int   smTI[196];
  __shared__ float smTW[196];
  int n = blockIdx.x, tid = threadIdx.x;
  if (tid < 49){
    const float* pd = paird + (size_t)n*136;
    int py = tid / 7, px = tid - (tid/7)*7;
    float x0 = pd[px],    wx = pd[7+px];
    float y0 = pd[14+py], wy = pd[21+py];
    int x0i = (int)x0, y0i = (int)y0;
    int x1i = min(x0i+1, 36), y1i = min(y0i+1, 36);
    smTI[tid*4+0] = (y0i*37+x0i)*256;
    smTI[tid*4+1] = (y0i*37+x1i)*256;
    smTI[tid*4+2] = (y1i*37+x0i)*256;
    smTI[tid*4+3] = (y1i*37+x1i)*256;
    smTW[tid*4+0] = (1.f-wy)*(1.f-wx);
    smTW[tid*4+1] = (1.f-wy)*wx;
    smTW[tid*4+2] = wy*(1.f-wx);
    smTW[tid*4+3] = wy*wx;
  }
  float a2 = ab2[tid*2+0], c2 = ab2[tid*2+1];   // tid == channel o
  __syncthreads();
  const uint16_t* zrow = zplus + (size_t)n*49*256 + tid;
  int o = tid;
  for (int pos=0; pos<49; pos++){
    float v = smTW[pos*4+0]*fmt[smTI[pos*4+0]+o]
            + smTW[pos*4+1]*fmt[smTI[pos*4+1]+o]
            + smTW[pos*4+2]*fmt[smTI[pos*4+2]+o]
            + smTW[pos*4+3]*fmt[smTI[pos*4+3]+o];
    float z = b2f(zrow[(size_t)pos*256]);
    smRes[o*49 + pos] = v + a2*z + c2;
  }
  __syncthreads();
  float* op = out + (size_t)n*12544;
  for (int i=0;i<49;i++){
    int f = tid + i*256;
    op[f] = smRes[f];
  }
}

// ----------------------------------------------------------- kernel_launch --
extern "C" void kernel_launch(void* const* d_in, const int* in_sizes, int n_in,
                              void* d_out, int out_size, void* d_ws, size_t ws_size,
                              hipStream_t stream)
{
  const float* fmap = (const float*)d_in[0];
  const float* rois = (const float*)d_in[1];
  const int*   ui   = (const int*)d_in[2];
  const float* W1   = (const float*)d_in[3];
  const float* b1   = (const float*)d_in[4];
  const float* g1   = (const float*)d_in[5];
  const float* be1  = (const float*)d_in[6];
  const float* W2   = (const float*)d_in[7];
  const float* b2   = (const float*)d_in[8];
  const float* g2   = (const float*)d_in[9];
  const float* be2  = (const float*)d_in[10];
  float* out = (float*)d_out;
  char* ws = (char*)d_ws;

  constexpr size_t OFF_ZERO = 0;                             // 256 B zero page
  constexpr size_t OFF_PAIR = 256;                           // 4096*136*4
  constexpr size_t OFF_FMT  = OFF_PAIR + 4096u*136*4;        // 350464*4
  constexpr size_t OFF_W1B  = OFF_FMT + 350464u*4;           // 16384*2
  constexpr size_t OFF_P1   = OFF_W1B + 16384u*2;            // 200704*128*2
  constexpr size_t OFF_ZP   = OFF_P1 + (size_t)200704*128*2; // 200704*256*2
  constexpr size_t OFF_W2S  = OFF_ZP + (size_t)200704*256*2; // 294912*2
  constexpr size_t OFF_T2   = OFF_W2S + 294912u*2;           // 12544*2
  constexpr size_t OFF_S1   = OFF_T2 + 12544u*2;             // 4096*128*2*4
  constexpr size_t OFF_AB1  = OFF_S1 + 4096u*128*2*4;        // 128*2*4
  constexpr size_t OFF_S2   = OFF_AB1 + 1024;                // 1568*256*2*4
  constexpr size_t OFF_AB2  = OFF_S2 + 1568u*256*2*4;        // 256*2*4

  float*    zp    = (float*)(ws + OFF_ZERO);
  float*    pair  = (float*)(ws + OFF_PAIR);
  float*    fmt   = (float*)(ws + OFF_FMT);
  uint16_t* W1b   = (uint16_t*)(ws + OFF_W1B);
  uint16_t* p1    = (uint16_t*)(ws + OFF_P1);
  uint16_t* zplus = (uint16_t*)(ws + OFF_ZP);
  uint16_t* W2s   = (uint16_t*)(ws + OFF_W2S);
  uint16_t* T2t   = (uint16_t*)(ws + OFF_T2);
  float*    part1 = (float*)(ws + OFF_S1);
  float*    ab1   = (float*)(ws + OFF_AB1);
  float*    part2 = (float*)(ws + OFF_S2);
  float*    ab2   = (float*)(ws + OFF_AB2);

  k_setup <<<16,   256, 0, stream>>>(rois, ui, pair, zp);
  k_prepw1<<<64,   256, 0, stream>>>(W1, W1b);
  k_fmapt <<<dim3(22,4), 256, 0, stream>>>(fmap, fmt);
  k_conv1 <<<4096, 512, 0, stream>>>(pair, W1b, b1, p1, part1);
  k_stats1<<<128,  256, 0, stream>>>(part1, g1, be1, ab1);
  k_prepb2<<<256,  256, 0, stream>>>(W2, b2, ab1, W2s, T2t);
  k_conv2 <<<1568, 256, 0, stream>>>(p1, W2s, T2t, zp, zplus, part2);
  k_stats2<<<256,  256, 0, stream>>>(part2, g2, be2, ab2);
  k_final <<<4096, 256, 0, stream>>>(pair, fmt, zplus, ab2, out);
}

// Round 5
// 592.045 us; speedup vs baseline: 2.1906x; 2.1906x over previous
//
#include <hip/hip_runtime.h>
#include <hip/hip_bf16.h>
#include <stdint.h>

// ---------------------------------------------------------------------------
// UnionBoxesAndFeats pipeline (R7):
//  k_setup   : per-pair union-roi sample coords + rect coverage vectors
//  k_prepw1  : W1 fp32 -> bf16 [128 o][128 k], k = c*64 + dy*8 + dx (padded)
//  k_fmapt   : fmap (C,H,W) -> (H*W, C), LDS-tiled transpose (both coalesced)
//  k_conv1   : per-pair MFMA GEMM; R7: epilogue stats/maxpool vectorized to
//              b64 LDS reads (was scalar u16 / u16x2 — 2-4x fewer LDS-port
//              instructions; epilogue was the port bottleneck, not MFMA)
//  k_stats1  : reduce partials -> a1,c1 (bn1 affine)
//  k_prepb2  : W2s = a1*W2 (bf16), T2t[pos][o] = b2 + pad-aware bn1-shift term
//  k_conv2   : implicit GEMM — REVERTED to R5 (166us known-good): triple-
//              buffer global_load_lds, 1 barrier/step, counted vmcnt(6),
//              frag reads interleaved under MFMA, XCD + XOR LDS swizzle.
//              (R6 zero-LDS gather was falsified: 16-segment 64B gathers
//              defeat L2 -> FETCH 34.5MB->1.44GB, 5x regression.)
//  k_stats2  : reduce -> a2,c2
//  k_final   : out = RoIAlign(union roi) + a2*z+ + c2; R7: float4 out copy
// ---------------------------------------------------------------------------

typedef __attribute__((ext_vector_type(8))) short bf16x8;
typedef __attribute__((ext_vector_type(4))) float f32x4;
typedef __attribute__((ext_vector_type(2))) unsigned short u16x2;
typedef __attribute__((ext_vector_type(4))) unsigned short u16x4;

__device__ __forceinline__ uint16_t f2b(float f) {          // fp32 -> bf16 RNE
  uint32_t x = __float_as_uint(f);
  return (uint16_t)((x + 0x7fffu + ((x >> 16) & 1u)) >> 16);
}
__device__ __forceinline__ float b2f(uint16_t u) {
  return __uint_as_float(((uint32_t)u) << 16);
}
__device__ __forceinline__ uint32_t pk2(float a, float b) { // packed RNE pair
  __hip_bfloat162 h = __float22bfloat162_rn(make_float2(a, b));
  union { __hip_bfloat162 h; uint32_t u; } cvt; cvt.h = h; return cvt.u;
}
__device__ __forceinline__ f32x4 mfma16(bf16x8 a, bf16x8 b, f32x4 c) {
  return __builtin_amdgcn_mfma_f32_16x16x32_bf16(a, b, c, 0, 0, 0);
}
__device__ __forceinline__ void gld16(void* l, const void* g) {
  __builtin_amdgcn_global_load_lds(
      (const __attribute__((address_space(1))) int*)g,
      (__attribute__((address_space(3))) int*)l, 16, 0, 0);
}

#define NPAIR 4096

// ---------------------------------------------------------------- k_setup ---
__global__ void k_setup(const float* __restrict__ rois, const int* __restrict__ ui,
                        float* __restrict__ paird, float* __restrict__ zp)
{
  int p = blockIdx.x * 256 + threadIdx.x;
  if (blockIdx.x == 0 && threadIdx.x < 64) zp[threadIdx.x] = 0.f;  // zero page
  if (p >= NPAIR) return;
  int i0 = ui[2*p+0], i1 = ui[2*p+1];
  const float* r0 = rois + i0*5;
  const float* r1 = rois + i1*5;
  float ax1=r0[1], ay1=r0[2], ax2=r0[3], ay2=r0[4];
  float bx1=r1[1], by1=r1[2], bx2=r1[3], by2=r1[4];
  float ux1=fminf(ax1,bx1), uy1=fminf(ay1,by1);
  float ux2=fmaxf(ax2,bx2), uy2=fmaxf(ay2,by2);
  float* pd = paird + (size_t)p*136;
  const float sc = 1.0f/16.0f;
  #pragma unroll
  for (int j=0;j<7;j++){
    float t = (float)j * (1.0f/6.0f);
    float xs = ux1*sc*(1.0f-t) + ux2*sc*t;
    xs = fminf(fmaxf(xs, 0.0f), 36.0f);
    float xf = floorf(xs);
    pd[j] = xf; pd[7+j] = xs - xf;
    float ys = uy1*sc*(1.0f-t) + uy2*sc*t;
    ys = fminf(fmaxf(ys, 0.0f), 36.0f);
    float yf = floorf(ys);
    pd[14+j] = yf; pd[21+j] = ys - yf;
  }
  float w = ux2-ux1, h = uy2-uy1;
  float x1a[2] = {ax1,bx1}, x2a[2] = {ax2,bx2};
  float y1a[2] = {ay1,by1}, y2a[2] = {ay2,by2};
  #pragma unroll
  for (int k=0;k<2;k++){
    float sx1 = (x1a[k]-ux1)/w*27.0f;
    float sx2 = (x2a[k]-ux1)/w*27.0f;
    float sy1 = (y1a[k]-uy1)/h*27.0f;
    float sy2 = (y2a[k]-uy1)/h*27.0f;
    for (int g=0; g<27; g++){
      float gg = (float)g;
      float cx = fminf(fmaxf(fminf(gg+1.0f, sx2) - fmaxf(gg, sx1), 0.0f), 1.0f);
      float cy = fminf(fmaxf(fminf(gg+1.0f, sy2) - fmaxf(gg, sy1), 0.0f), 1.0f);
      pd[28 + k*27 + g] = cx;   // cx ch0@28, ch1@55
      pd[82 + k*27 + g] = cy;   // cy ch0@82, ch1@109
    }
  }
}

// --------------------------------------------------------------- k_prepw1 ---
// W1b[o][k], k = cch*64 + dy*8 + dx  (dy,dx in 0..6 real, slot 7 zero)
__global__ void k_prepw1(const float* __restrict__ W1, uint16_t* __restrict__ W1b)
{
  int idx = blockIdx.x*256 + threadIdx.x;   // 64 blocks -> 16384
  int o = idx >> 7, kk = idx & 127;
  int cch = kk >> 6, r = kk & 63, dy = r >> 3, dx = r & 7;
  float v = (dy < 7 && dx < 7) ? W1[o*98 + cch*49 + dy*7 + dx] : 0.f;
  W1b[idx] = f2b(v);
}

// ---------------------------------------------------------------- k_fmapt ---
// tiled transpose: 64 (yx) x 64 (o) tiles; grid (22, 4)
__global__ void k_fmapt(const float* __restrict__ fmap, float* __restrict__ fmt){
  __shared__ float tile[64][65];
  int yx0 = blockIdx.x * 64;
  int o0  = blockIdx.y * 64;
  int tx = threadIdx.x & 63, ty = threadIdx.x >> 6;
  #pragma unroll
  for (int i=0;i<16;i++){
    int oo = ty*16 + i;
    int yx = yx0 + tx;
    tile[oo][tx] = (yx < 1369) ? fmap[(size_t)(o0+oo)*1369 + yx] : 0.f;
  }
  __syncthreads();
  #pragma unroll
  for (int i=0;i<16;i++){
    int r = ty*16 + i;
    int yx = yx0 + r;
    if (yx < 1369) fmt[(size_t)yx*256 + o0 + tx] = tile[tx][r];
  }
}

// ---------------------------------------------------------------- k_conv1 ---
// one block per pair, 512 threads. GEMM (o=128) x (m=256 pad, 196 real) x
// (k=128 pad, 98 real), operand-swapped: D rows = o, cols = m.
__global__ __launch_bounds__(512, 4) void k_conv1(
    const float* __restrict__ paird, const uint16_t* __restrict__ W1b,
    const float* __restrict__ b1v,
    uint16_t* __restrict__ p1, float* __restrict__ part1)
{
  __shared__ __align__(128) char lds[62976];
  uint16_t* smA  = (uint16_t*)lds;              // [256 m][72] per-64k chunk
  uint16_t* smB  = (uint16_t*)(lds + 36864);    // [128 o][72]
  uint16_t* smY  = (uint16_t*)lds;              // [196 m][132 o] epilogue (overlaps)
  float* cy0a = (float*)(lds + 55296);          // [14][8]
  float* cy1a = (float*)(lds + 55808);
  float* bya  = (float*)(lds + 56320);
  float* cx0a = (float*)(lds + 56832);
  float* cx1a = (float*)(lds + 57344);
  float* nbxa = (float*)(lds + 57856);
  float* smB1 = (float*)(lds + 58368);          // [128]
  float* smStat = (float*)(lds + 58880);        // [128][8]
  const int tid = threadIdx.x;
  const int n = blockIdx.x;
  const int wv = tid >> 6, lane = tid & 63, quad = lane >> 4, l15 = lane & 15;
  const float* pd = paird + (size_t)n*136;

  // phase 0: coverage lookup tables (slot dy/dx==7 -> 0)
  if (tid < 112){
    int Y = tid >> 3, dy = tid & 7;
    int yq = 2*Y + dy - 3;
    bool iy = (dy < 7) && ((unsigned)yq < 27u);
    int yqc = iy ? yq : 0;
    cy0a[tid] = iy ? pd[82+yqc]  : 0.f;
    cy1a[tid] = iy ? pd[109+yqc] : 0.f;
    bya[tid]  = iy ? 1.f : 0.f;
  } else if (tid >= 128 && tid < 240){
    int t2 = tid - 128;
    int X = t2 >> 3, dx = t2 & 7;
    int xq = 2*X + dx - 3;
    bool ix = (dx < 7) && ((unsigned)xq < 27u);
    int xqc = ix ? xq : 0;
    cx0a[t2] = ix ? pd[28+xqc] : 0.f;
    cx1a[t2] = ix ? pd[55+xqc] : 0.f;
    nbxa[t2] = ix ? -0.5f : 0.f;
  } else if (tid >= 256 && tid < 384){
    smB1[tid-256] = b1v[tid-256];
  }
  __syncthreads();

  const int m = tid & 255, h = tid >> 8;        // thread -> (A row, k-half)
  int Yr = m / 14, Xr = m - (m/14)*14;
  bool mv = (m < 196);
  int Yc = mv ? Yr : 0, Xc = mv ? Xr : 0;
  float byr[4], nbr[8];
  #pragma unroll
  for (int j=0;j<4;j++) byr[j] = mv ? bya[Yc*8 + h*4 + j] : 0.f;
  #pragma unroll
  for (int d=0;d<8;d++) nbr[d] = mv ? nbxa[Xc*8 + d] : 0.f;

  f32x4 zero4 = {0.f,0.f,0.f,0.f};
  f32x4 acc[8][2];
  #pragma unroll
  for (int io=0;io<8;io++){ acc[io][0] = zero4; acc[io][1] = zero4; }

  #pragma unroll
  for (int c=0;c<2;c++){
    // stage B chunk (bf16, already padded/ordered)
    {
      int o = tid >> 2, part = tid & 3;
      const uint4* src = (const uint4*)(W1b + o*128 + c*64);
      uint4* dst = (uint4*)(smB + o*72);
      dst[part*2]   = src[part*2];
      dst[part*2+1] = src[part*2+1];
    }
    // generate A chunk: k-local = dy*8+dx; per g, dy = h*4+g fixed
    {
      const float* cya = c ? cy1a : cy0a;
      const float* cxa = c ? cx1a : cx0a;
      float cyr[4], cxr[8];
      #pragma unroll
      for (int j=0;j<4;j++) cyr[j] = mv ? cya[Yc*8 + h*4 + j] : 0.f;
      #pragma unroll
      for (int d=0;d<8;d++) cxr[d] = mv ? cxa[Xc*8 + d] : 0.f;
      uint16_t* rowp = smA + m*72 + h*32;
      #pragma unroll
      for (int g=0; g<4; g++){
        uint32_t w[4];
        #pragma unroll
        for (int q=0; q<4; q++){
          float v0 = fmaf(cyr[g], cxr[q*2],   byr[g]*nbr[q*2]);
          float v1 = fmaf(cyr[g], cxr[q*2+1], byr[g]*nbr[q*2+1]);
          w[q] = pk2(v0, v1);
        }
        *(uint4*)(rowp + g*8) = make_uint4(w[0],w[1],w[2],w[3]);
      }
    }
    __syncthreads();
    #pragma unroll
    for (int ks=0; ks<2; ks++){
      bf16x8 rf0 = *(const bf16x8*)(smA + (wv*32      + l15)*72 + ks*32 + quad*8);
      bf16x8 rf1 = *(const bf16x8*)(smA + (wv*32 + 16 + l15)*72 + ks*32 + quad*8);
      #pragma unroll
      for (int io=0;io<8;io++){
        bf16x8 wf = *(const bf16x8*)(smB + (io*16 + l15)*72 + ks*32 + quad*8);
        acc[io][0] = mfma16(wf, rf0, acc[io][0]);
        acc[io][1] = mfma16(wf, rf1, acc[io][1]);
      }
    }
    __syncthreads();
  }

  // epilogue: y[m][o] = relu(acc + b1) -> smY, packed b64 writes
  #pragma unroll
  for (int io=0;io<8;io++){
    f32x4 bs = *(const f32x4*)(smB1 + io*16 + quad*4);
    #pragma unroll
    for (int jm=0;jm<2;jm++){
      int mm = wv*32 + jm*16 + l15;
      if (mm < 196){
        float v0 = fmaxf(acc[io][jm][0] + bs[0], 0.f);
        float v1 = fmaxf(acc[io][jm][1] + bs[1], 0.f);
        float v2 = fmaxf(acc[io][jm][2] + bs[2], 0.f);
        float v3 = fmaxf(acc[io][jm][3] + bs[3], 0.f);
        uint32_t w0 = pk2(v0,v1) & 0x7fff7fffu;   // clear -0 signs (u16 max safe)
        uint32_t w1 = pk2(v2,v3) & 0x7fff7fffu;
        *(uint2*)(smY + mm*132 + io*16 + quad*4) = make_uint2(w0, w1);
      }
    }
  }
  __syncthreads();

  // per-channel stats partials over 196 positions — b64 reads, 128 threads
  // (4x fewer LDS-port instructions than the scalar-u16 version)
  if (tid < 128){
    int oq = (tid & 31) * 4, hh = tid >> 5;     // 32 ch-quads x 4 row-groups
    float S0=0.f,S1=0.f,S2=0.f,S3=0.f,Q0=0.f,Q1=0.f,Q2=0.f,Q3=0.f;
    for (int r = hh*49; r < hh*49 + 49; r++){
      u16x4 v = *(const u16x4*)(smY + r*132 + oq);
      float f0 = b2f(v[0]), f1 = b2f(v[1]), f2 = b2f(v[2]), f3 = b2f(v[3]);
      S0 += f0; Q0 += f0*f0;
      S1 += f1; Q1 += f1*f1;
      S2 += f2; Q2 += f2*f2;
      S3 += f3; Q3 += f3*f3;
    }
    smStat[(oq+0)*8 + hh*2 + 0] = S0; smStat[(oq+0)*8 + hh*2 + 1] = Q0;
    smStat[(oq+1)*8 + hh*2 + 0] = S1; smStat[(oq+1)*8 + hh*2 + 1] = Q1;
    smStat[(oq+2)*8 + hh*2 + 0] = S2; smStat[(oq+2)*8 + hh*2 + 1] = Q2;
    smStat[(oq+3)*8 + hh*2 + 0] = S3; smStat[(oq+3)*8 + hh*2 + 1] = Q3;
  }

  // maxpool 3x3 s2 via packed u16x4 integer max (values >= 0, signs cleared)
  #pragma unroll
  for (int it=0; it<4; it++){
    int idx = tid + it*512;
    if (idx < 1568){                            // 49 pos x 32 ch-quads
      int pos = idx >> 5, oq = (idx & 31)*4;
      int Yp = pos / 7, Xp = pos - Yp*7;
      int yb = 2*Yp - 1, xb = 2*Xp - 1;
      u16x4 mx = {0,0,0,0};
      #pragma unroll
      for (int a=0;a<3;a++){
        int yy = yb + a;
        if ((unsigned)yy < 14u){
          #pragma unroll
          for (int b=0;b<3;b++){
            int xx = xb + b;
            if ((unsigned)xx < 14u){
              u16x4 v = *(const u16x4*)(smY + (yy*14+xx)*132 + oq);
#if defined(__has_builtin) && __has_builtin(__builtin_elementwise_max)
              mx = __builtin_elementwise_max(mx, v);
#else
              mx[0] = mx[0] > v[0] ? mx[0] : v[0];
              mx[1] = mx[1] > v[1] ? mx[1] : v[1];
              mx[2] = mx[2] > v[2] ? mx[2] : v[2];
              mx[3] = mx[3] > v[3] ? mx[3] : v[3];
#endif
            }
          }
        }
      }
      *(uint2*)(p1 + ((size_t)n*49 + pos)*128 + oq) = *(uint2*)&mx;
    }
  }
  __syncthreads();
  if (tid < 128){
    float S = smStat[tid*8+0] + smStat[tid*8+2] + smStat[tid*8+4] + smStat[tid*8+6];
    float Q = smStat[tid*8+1] + smStat[tid*8+3] + smStat[tid*8+5] + smStat[tid*8+7];
    part1[((size_t)n*128 + tid)*2 + 0] = S;
    part1[((size_t)n*128 + tid)*2 + 1] = Q;
  }
}

// --------------------------------------------------------------- k_stats1 ---
__global__ void k_stats1(const float* __restrict__ part1, const float* __restrict__ g1,
                         const float* __restrict__ be1, float* __restrict__ ab1)
{
  __shared__ float sS[256], sQ[256];
  int ch = blockIdx.x, t = threadIdx.x;
  float S=0.f, Q=0.f;
  for (int i=t; i<4096; i+=256){
    S += part1[((size_t)i*128 + ch)*2 + 0];
    Q += part1[((size_t)i*128 + ch)*2 + 1];
  }
  sS[t]=S; sQ[t]=Q;
  __syncthreads();
  for (int s=128; s>0; s>>=1){
    if (t < s){ sS[t]+=sS[t+s]; sQ[t]+=sQ[t+s]; }
    __syncthreads();
  }
  if (t==0){
    float N = 4096.0f*196.0f;
    float mean = sS[0]/N;
    float var = sQ[0]/N - mean*mean;
    float a = g1[ch] * rsqrtf(var + 1e-5f);
    ab1[ch*2+0] = a;
    ab1[ch*2+1] = be1[ch] - mean*a;
  }
}

// --------------------------------------------------------------- k_prepb2 ---
__global__ void k_prepb2(const float* __restrict__ W2, const float* __restrict__ b2v,
                         const float* __restrict__ ab1,
                         uint16_t* __restrict__ W2s, uint16_t* __restrict__ T2t)
{
  __shared__ float sA[128], sC[128], sU[9];
  int o = blockIdx.x, t = threadIdx.x;
  if (t < 128){ sA[t] = ab1[t*2+0]; sC[t] = ab1[t*2+1]; }
  __syncthreads();
  const float* w = W2 + (size_t)o*1152;
  for (int k=t; k<1152; k+=256){
    int c = k & 127, tap = k >> 7;
    W2s[(size_t)o*1152 + k] = f2b(w[c*9 + tap] * sA[c]);
  }
  if (t < 9){
    float u = 0.f;
    for (int c=0;c<128;c++) u += sC[c] * w[c*9 + t];
    sU[t] = u;
  }
  __syncthreads();
  if (t < 49){
    int y = t / 7, x = t - (t/7)*7;
    float s = b2v[o];
    #pragma unroll
    for (int dy=0;dy<3;dy++)
      #pragma unroll
      for (int dx=0;dx<3;dx++){
        int yy = y+dy-1, xx = x+dx-1;
        if ((unsigned)yy < 7u && (unsigned)xx < 7u) s += sU[dy*3+dx];
      }
    T2t[t*256 + o] = f2b(s);
  }
}

// ---------------------------------------------------------------- k_conv2 ---
// implicit GEMM: M=200704 (tile 128), N=256, K=1152 in 36 steps of BK=32.
// R5 pipeline (reverted from R6): TRIPLE buffer (3 x 24KB), ONE barrier/step.
//   iter s: stage(s+2)->buf[(s+2)%3]; s_waitcnt vmcnt(6) lgkmcnt(0);
//           s_barrier; MFMA(step s) with frag reads for s+1 interleaved
//           into just-dead registers (WAR reuse -> no extra VGPRs).
// Swizzle (both sides, involution): within each 16-row x 64B group (1KB),
// logical (row r, 16B-chunk c) lives at physical slot p = (r>>1)*8 + cc',
// cc' = (c + 4*(r&1)) ^ ((r>>1)&7); staging decodes (r,c) from p=lane.
__global__ __launch_bounds__(256, 2) void k_conv2(
    const uint16_t* __restrict__ p1, const uint16_t* __restrict__ W2s,
    const uint16_t* __restrict__ T2t, const float* __restrict__ zpf,
    uint16_t* __restrict__ zplus, float* __restrict__ part2)
{
  __shared__ __align__(128) char lds[73728];   // 3 x (A 8KB + B 16KB)
  const int tid = threadIdx.x;
  // XCD-bijective swizzle: 1568 % 8 == 0 -> contiguous 196-tile chunk per XCD
  const int bid = blockIdx.x;
  const int swz = (bid & 7) * 196 + (bid >> 3);
  const int m0 = swz * 128;
  const int wv = tid >> 6, lane = tid & 63, quad = lane >> 4, l15 = lane & 15;
  const int wm = wv >> 1, wn = wv & 1;

  // staging swizzle decode: physical slot 'lane' -> logical (row slr, chunk)
  const int sg   = lane >> 3;                  // row-pair within 16-row group
  const int scc  = (lane & 7) ^ (sg & 7);
  const int slr  = (sg << 1) + (scc >> 2);     // logical row 0..15
  const int coff = (scc & 3) << 4;             // logical chunk byte offset

  const char* p1c = (const char*)p1;
  const char* w2c = (const char*)W2s;
  const char* zpc = (const char*)zpf;

  // A-row geometry for this lane's two staged rows (groups wv*2, wv*2+1)
  int abase0; unsigned amask = 0;
  {
    int mm0 = m0 + ((wv*2) << 4) + slr;
    abase0 = (mm0 << 8) + coff;                // byte offset of center tap
    #pragma unroll
    for (int i=0;i<2;i++){
      int mm = mm0 + (i << 4);
      int nn = mm / 49;
      int pp = mm - nn*49;
      int yy = pp / 7;
      int xx = pp - yy*7;
      unsigned mk = 0;
      #pragma unroll
      for (int dy=0; dy<3; dy++)
        #pragma unroll
        for (int dx=0; dx<3; dx++){
          int y2 = yy + dy - 1, x2 = xx + dx - 1;
          if ((unsigned)y2 < 7u && (unsigned)x2 < 7u) mk |= 1u << (dy*3+dx);
        }
      amask |= mk << (i*9);
    }
  }
  // B source offsets (groups wv*4 .. wv*4+3), row stride 1152*2 = 2304 B
  int bbase[4];
  #pragma unroll
  for (int i=0;i<4;i++) bbase[i] = (((wv*4+i) << 4) + slr)*2304 + coff;

  // fragment read offsets (swizzled); offA[ia+2]=offA[ia]+2048, offB[jb+4]=+4096
  int offA[2], offB[4];
  #pragma unroll
  for (int ia=0; ia<2; ia++){
    int row = wm*64 + ia*16 + l15;
    offA[ia] = ((row>>4)<<10) + (((row>>1)&7)<<7)
             + (((quad + ((row&1)<<2)) ^ ((row>>1)&7)) << 4);
  }
  #pragma unroll
  for (int jb=0; jb<4; jb++){
    int row = wn*128 + jb*16 + l15;
    offB[jb] = 8192 + ((row>>4)<<10) + (((row>>1)&7)<<7)
             + (((quad + ((row&1)<<2)) ^ ((row>>1)&7)) << 4);
  }

  auto stage = [&](int s, char* dst){
    int tap = s >> 2;                          // 0..8 (uniform)
    int dy = tap / 3, dx = tap - dy*3;
    int tdelta = (((dy-1)*7 + (dx-1)) << 8) + ((s & 3) << 6);
    const char* a0 = ((amask >> tap) & 1u)       ? (p1c + (abase0 + tdelta))
                                                 : (zpc + coff);
    const char* a1 = ((amask >> (tap + 9)) & 1u) ? (p1c + (abase0 + 4096 + tdelta))
                                                 : (zpc + coff);
    gld16(dst + (wv*2+0)*1024, a0);
    gld16(dst + (wv*2+1)*1024, a1);
    int bko = s << 6;
    #pragma unroll
    for (int i=0;i<4;i++)
      gld16(dst + 8192 + (wv*4+i)*1024, w2c + (bbase[i] + bko));
  };

  f32x4 zero4 = {0.f,0.f,0.f,0.f};
  f32x4 acc[4][8];
  #pragma unroll
  for (int ia=0;ia<4;ia++)
    #pragma unroll
    for (int jb=0;jb<8;jb++) acc[ia][jb] = zero4;

  // prologue: stage 0,1; wait stage0 landed; read frags(0)
  stage(0, lds);
  stage(1, lds + 24576);
  asm volatile("s_waitcnt vmcnt(6)" ::: "memory");
  __builtin_amdgcn_s_barrier();
  __builtin_amdgcn_sched_barrier(0);

  bf16x8 af[4], bb[8];
  #pragma unroll
  for (int ia=0;ia<4;ia++)
    af[ia] = *(const bf16x8*)(lds + (offA[ia&1] + ((ia>>1)<<11)));
  #pragma unroll
  for (int jb=0;jb<8;jb++)
    bb[jb] = *(const bf16x8*)(lds + (offB[jb&3] + ((jb>>2)<<12)));

  int c1 = 1, c2 = 2;                          // (s+1)%3, (s+2)%3
  for (int s=0; s<36; s++){
    if (s < 34) stage(s+2, lds + c2*24576);
    if (s < 35){
      if (s < 34) asm volatile("s_waitcnt vmcnt(6) lgkmcnt(0)" ::: "memory");
      else        asm volatile("s_waitcnt vmcnt(0) lgkmcnt(0)" ::: "memory");
      __builtin_amdgcn_s_barrier();
      __builtin_amdgcn_sched_barrier(0);
    }
    const char* nb = lds + c1*24576;
    __builtin_amdgcn_s_setprio(1);
    if (s < 35){
      #pragma unroll
      for (int jb=0;jb<8;jb++){
        #pragma unroll
        for (int ia=0;ia<4;ia++){
          acc[ia][jb] = mfma16(af[ia], bb[jb], acc[ia][jb]);
          if (jb == 7)                         // af[ia] dead after last group
            af[ia] = *(const bf16x8*)(nb + (offA[ia&1] + ((ia>>1)<<11)));
        }
        bb[jb] = *(const bf16x8*)(nb + (offB[jb&3] + ((jb>>2)<<12)));
      }
    } else {
      #pragma unroll
      for (int jb=0;jb<8;jb++)
        #pragma unroll
        for (int ia=0;ia<4;ia++)
          acc[ia][jb] = mfma16(af[ia], bb[jb], acc[ia][jb]);
    }
    __builtin_amdgcn_s_setprio(0);
    c1 = (c1 == 2) ? 0 : c1 + 1;
    c2 = (c2 == 2) ? 0 : c2 + 1;
  }
  __syncthreads();   // drain + sync before repurposing LDS (no gld16 pending)

  // ---- epilogue: bias+relu -> bf16, transpose via LDS in 4 quarters of 32 m
  uint16_t* smT = (uint16_t*)(lds + 16384);     // [49][256] bias table (24.5KB)
  #pragma unroll
  for (int i=0;i<7;i++){
    int ch = tid + i*256;
    if (ch < 1568) ((uint4*)smT)[ch] = ((const uint4*)T2t)[ch];
  }
  uint16_t* smZ = (uint16_t*)lds;               // [32][256] quarter buffer
  float S = 0.f, Q = 0.f;
  #pragma unroll
  for (int q=0; q<4; q++){
    __syncthreads();
    if (wm == (q>>1)){
      #pragma unroll
      for (int t2=0;t2<2;t2++){
        int ia = ((q&1)<<1) + t2;
        #pragma unroll
        for (int reg=0; reg<4; reg++){
          int rl = t2*16 + quad*4 + reg;        // row within quarter
          int mm = m0 + q*32 + rl;
          int pos = mm % 49;
          const uint16_t* tr = smT + pos*256 + wn*128;
          uint16_t* zr = smZ + rl*256 + wn*128;
          #pragma unroll
          for (int jb=0;jb<8;jb++){
            int col = jb*16 + l15;
            float z = acc[ia][jb][reg] + b2f(tr[col]);
            zr[col] = f2b(fmaxf(z, 0.0f));
          }
        }
      }
    }
    __syncthreads();
    #pragma unroll
    for (int i2=0;i2<4;i2++){
      int idx = tid + i2*256;                   // 1024 uint4 = 16KB
      int row = idx >> 5, off = idx & 31;
      *(uint4*)(zplus + ((size_t)(m0 + q*32 + row))*256 + off*8) = ((const uint4*)smZ)[idx];
    }
    for (int r=0;r<32;r++){
      float v = b2f(smZ[r*256 + tid]);
      S += v; Q += v*v;
    }
  }
  part2[((size_t)swz*256 + tid)*2 + 0] = S;
  part2[((size_t)swz*256 + tid)*2 + 1] = Q;
}

// --------------------------------------------------------------- k_stats2 ---
__global__ void k_stats2(const float* __restrict__ part2, const float* __restrict__ g2,
                         const float* __restrict__ be2, float* __restrict__ ab2)
{
  __shared__ float sS[256], sQ[256];
  int ch = blockIdx.x, t = threadIdx.x;
  float S=0.f, Q=0.f;
  for (int i=t; i<1568; i+=256){
    S += part2[((size_t)i*256 + ch)*2 + 0];
    Q += part2[((size_t)i*256 + ch)*2 + 1];
  }
  sS[t]=S; sQ[t]=Q;
  __syncthreads();
  for (int s=128; s>0; s>>=1){
    if (t < s){ sS[t]+=sS[t+s]; sQ[t]+=sQ[t+s]; }
    __syncthreads();
  }
  if (t==0){
    float N = 200704.0f;
    float mean = sS[0]/N;
    float var = sQ[0]/N - mean*mean;
    float a = g2[ch] * rsqrtf(var + 1e-5f);
    ab2[ch*2+0] = a;
    ab2[ch*2+1] = be2[ch] - mean*a;
  }
}

// ---------------------------------------------------------------- k_final ---
__global__ __launch_bounds__(256) void k_final(
    const float* __restrict__ paird, const float* __restrict__ fmt,
    const uint16_t* __restrict__ zplus, const float* __restrict__ ab2,
    float* __restrict__ out)
{
  __shared__ float smRes[12544];     // [o][pos] transpose buffer
  __shared__ int   smTI[196];
  __shared__ float smTW[196];
  int n = blockIdx.x, tid = threadIdx.x;
  if (tid < 49){
    const float* pd = paird + (size_t)n*136;
    int py = tid / 7, px = tid - (tid/7)*7;
    float x0 = pd[px],    wx = pd[7+px];
    float y0 = pd[14+py], wy = pd[21+py];
    int x0i = (int)x0, y0i = (int)y0;
    int x1i = min(x0i+1, 36), y1i = min(y0i+1, 36);
    smTI[tid*4+0] = (y0i*37+x0i)*256;
    smTI[tid*4+1] = (y0i*37+x1i)*256;
    smTI[tid*4+2] = (y1i*37+x0i)*256;
    smTI[tid*4+3] = (y1i*37+x1i)*256;
    smTW[tid*4+0] = (1.f-wy)*(1.f-wx);
    smTW[tid*4+1] = (1.f-wy)*wx;
    smTW[tid*4+2] = wy*(1.f-wx);
    smTW[tid*4+3] = wy*wx;
  }
  float a2 = ab2[tid*2+0], c2 = ab2[tid*2+1];   // tid == channel o
  __syncthreads();
  const uint16_t* zrow = zplus + (size_t)n*49*256 + tid;
  int o = tid;
  for (int pos=0; pos<49; pos++){
    float v = smTW[pos*4+0]*fmt[smTI[pos*4+0]+o]
            + smTW[pos*4+1]*fmt[smTI[pos*4+1]+o]
            + smTW[pos*4+2]*fmt[smTI[pos*4+2]+o]
            + smTW[pos*4+3]*fmt[smTI[pos*4+3]+o];
    float z = b2f(zrow[(size_t)pos*256]);
    smRes[o*49 + pos] = v + a2*z + c2;
  }
  __syncthreads();
  float* op = out + (size_t)n*12544;
  #pragma unroll
  for (int i=0;i<13;i++){
    int idx = tid + i*256;                      // 3136 float4 = 12544 floats
    if (idx < 3136)
      ((float4*)op)[idx] = ((const float4*)smRes)[idx];
  }
}

// ----------------------------------------------------------- kernel_launch --
extern "C" void kernel_launch(void* const* d_in, const int* in_sizes, int n_in,
                              void* d_out, int out_size, void* d_ws, size_t ws_size,
                              hipStream_t stream)
{
  const float* fmap = (const float*)d_in[0];
  const float* rois = (const float*)d_in[1];
  const int*   ui   = (const int*)d_in[2];
  const float* W1   = (const float*)d_in[3];
  const float* b1   = (const float*)d_in[4];
  const float* g1   = (const float*)d_in[5];
  const float* be1  = (const float*)d_in[6];
  const float* W2   = (const float*)d_in[7];
  const float* b2   = (const float*)d_in[8];
  const float* g2   = (const float*)d_in[9];
  const float* be2  = (const float*)d_in[10];
  float* out = (float*)d_out;
  char* ws = (char*)d_ws;

  constexpr size_t OFF_ZERO = 0;                             // 256 B zero page
  constexpr size_t OFF_PAIR = 256;                           // 4096*136*4
  constexpr size_t OFF_FMT  = OFF_PAIR + 4096u*136*4;        // 350464*4
  constexpr size_t OFF_W1B  = OFF_FMT + 350464u*4;           // 16384*2
  constexpr size_t OFF_P1   = OFF_W1B + 16384u*2;            // 200704*128*2
  constexpr size_t OFF_ZP   = OFF_P1 + (size_t)200704*128*2; // 200704*256*2
  constexpr size_t OFF_W2S  = OFF_ZP + (size_t)200704*256*2; // 294912*2
  constexpr size_t OFF_T2   = OFF_W2S + 294912u*2;           // 12544*2
  constexpr size_t OFF_S1   = OFF_T2 + 12544u*2;             // 4096*128*2*4
  constexpr size_t OFF_AB1  = OFF_S1 + 4096u*128*2*4;        // 128*2*4
  constexpr size_t OFF_S2   = OFF_AB1 + 1024;                // 1568*256*2*4
  constexpr size_t OFF_AB2  = OFF_S2 + 1568u*256*2*4;        // 256*2*4

  float*    zp    = (float*)(ws + OFF_ZERO);
  float*    pair  = (float*)(ws + OFF_PAIR);
  float*    fmt   = (float*)(ws + OFF_FMT);
  uint16_t* W1b   = (uint16_t*)(ws + OFF_W1B);
  uint16_t* p1    = (uint16_t*)(ws + OFF_P1);
  uint16_t* zplus = (uint16_t*)(ws + OFF_ZP);
  uint16_t* W2s   = (uint16_t*)(ws + OFF_W2S);
  uint16_t* T2t   = (uint16_t*)(ws + OFF_T2);
  float*    part1 = (float*)(ws + OFF_S1);
  float*    ab1   = (float*)(ws + OFF_AB1);
  float*    part2 = (float*)(ws + OFF_S2);
  float*    ab2   = (float*)(ws + OFF_AB2);

  k_setup <<<16,   256, 0, stream>>>(rois, ui, pair, zp);
  k_prepw1<<<64,   256, 0, stream>>>(W1, W1b);
  k_fmapt <<<dim3(22,4), 256, 0, stream>>>(fmap, fmt);
  k_conv1 <<<4096, 512, 0, stream>>>(pair, W1b, b1, p1, part1);
  k_stats1<<<128,  256, 0, stream>>>(part1, g1, be1, ab1);
  k_prepb2<<<256,  256, 0, stream>>>(W2, b2, ab1, W2s, T2t);
  k_conv2 <<<1568, 256, 0, stream>>>(p1, W2s, T2t, zp, zplus, part2);
  k_stats2<<<256,  256, 0, stream>>>(part2, g2, be2, ab2);
  k_final <<<4096, 256, 0, stream>>>(pair, fmt, zplus, ab2, out);
}

// Round 6
// 591.341 us; speedup vs baseline: 2.1932x; 1.0012x over previous
//
#include <hip/hip_runtime.h>
#include <hip/hip_bf16.h>
#include <stdint.h>

// ---------------------------------------------------------------------------
// UnionBoxesAndFeats pipeline (R8):
//  k_setup   : per-pair union-roi sample coords + rect coverage vectors
//  k_prepw1  : W1 fp32 -> bf16 [128 o][128 k], k = c*64 + dy*8 + dx (padded)
//  k_fmapt   : fmap (C,H,W) -> (H*W, C), LDS-tiled transpose (both coalesced)
//  k_conv1   : per-pair MFMA GEMM (R7: b64 epilogue)
//  k_stats1  : reduce partials -> a1,c1 (bn1 affine)
//  k_prepb2  : W2s = a1*W2 (bf16), T2t[pos][o] = b2 + pad-aware bn1-shift term
//  k_conv2   : implicit GEMM — R8: N-SPLIT 128x128 tiles (grid 3136) to cut
//              acc to 64 AGPR -> total regs <=170 -> 3 blocks/CU (was 2,
//              register-pinned at 252 regs). Same triple-buffer counted-
//              vmcnt pipeline (now vmcnt(4): 4 gld16/stage), same XOR LDS
//              swizzle; XCD swizzle on m-tile so both N-halves share an XCD.
//  k_stats2  : reduce -> a2,c2 (unchanged; in-block hh-reduce keeps layout)
//  k_final   : out = RoIAlign(union roi) + a2*z+ + c2 (R7 float4 copy)
// ---------------------------------------------------------------------------

typedef __attribute__((ext_vector_type(8))) short bf16x8;
typedef __attribute__((ext_vector_type(4))) float f32x4;
typedef __attribute__((ext_vector_type(2))) unsigned short u16x2;
typedef __attribute__((ext_vector_type(4))) unsigned short u16x4;

__device__ __forceinline__ uint16_t f2b(float f) {          // fp32 -> bf16 RNE
  uint32_t x = __float_as_uint(f);
  return (uint16_t)((x + 0x7fffu + ((x >> 16) & 1u)) >> 16);
}
__device__ __forceinline__ float b2f(uint16_t u) {
  return __uint_as_float(((uint32_t)u) << 16);
}
__device__ __forceinline__ uint32_t pk2(float a, float b) { // packed RNE pair
  __hip_bfloat162 h = __float22bfloat162_rn(make_float2(a, b));
  union { __hip_bfloat162 h; uint32_t u; } cvt; cvt.h = h; return cvt.u;
}
__device__ __forceinline__ f32x4 mfma16(bf16x8 a, bf16x8 b, f32x4 c) {
  return __builtin_amdgcn_mfma_f32_16x16x32_bf16(a, b, c, 0, 0, 0);
}
__device__ __forceinline__ void gld16(void* l, const void* g) {
  __builtin_amdgcn_global_load_lds(
      (const __attribute__((address_space(1))) int*)g,
      (__attribute__((address_space(3))) int*)l, 16, 0, 0);
}

#define NPAIR 4096

// ---------------------------------------------------------------- k_setup ---
__global__ void k_setup(const float* __restrict__ rois, const int* __restrict__ ui,
                        float* __restrict__ paird, float* __restrict__ zp)
{
  int p = blockIdx.x * 256 + threadIdx.x;
  if (blockIdx.x == 0 && threadIdx.x < 64) zp[threadIdx.x] = 0.f;  // zero page
  if (p >= NPAIR) return;
  int i0 = ui[2*p+0], i1 = ui[2*p+1];
  const float* r0 = rois + i0*5;
  const float* r1 = rois + i1*5;
  float ax1=r0[1], ay1=r0[2], ax2=r0[3], ay2=r0[4];
  float bx1=r1[1], by1=r1[2], bx2=r1[3], by2=r1[4];
  float ux1=fminf(ax1,bx1), uy1=fminf(ay1,by1);
  float ux2=fmaxf(ax2,bx2), uy2=fmaxf(ay2,by2);
  float* pd = paird + (size_t)p*136;
  const float sc = 1.0f/16.0f;
  #pragma unroll
  for (int j=0;j<7;j++){
    float t = (float)j * (1.0f/6.0f);
    float xs = ux1*sc*(1.0f-t) + ux2*sc*t;
    xs = fminf(fmaxf(xs, 0.0f), 36.0f);
    float xf = floorf(xs);
    pd[j] = xf; pd[7+j] = xs - xf;
    float ys = uy1*sc*(1.0f-t) + uy2*sc*t;
    ys = fminf(fmaxf(ys, 0.0f), 36.0f);
    float yf = floorf(ys);
    pd[14+j] = yf; pd[21+j] = ys - yf;
  }
  float w = ux2-ux1, h = uy2-uy1;
  float x1a[2] = {ax1,bx1}, x2a[2] = {ax2,bx2};
  float y1a[2] = {ay1,by1}, y2a[2] = {ay2,by2};
  #pragma unroll
  for (int k=0;k<2;k++){
    float sx1 = (x1a[k]-ux1)/w*27.0f;
    float sx2 = (x2a[k]-ux1)/w*27.0f;
    float sy1 = (y1a[k]-uy1)/h*27.0f;
    float sy2 = (y2a[k]-uy1)/h*27.0f;
    for (int g=0; g<27; g++){
      float gg = (float)g;
      float cx = fminf(fmaxf(fminf(gg+1.0f, sx2) - fmaxf(gg, sx1), 0.0f), 1.0f);
      float cy = fminf(fmaxf(fminf(gg+1.0f, sy2) - fmaxf(gg, sy1), 0.0f), 1.0f);
      pd[28 + k*27 + g] = cx;   // cx ch0@28, ch1@55
      pd[82 + k*27 + g] = cy;   // cy ch0@82, ch1@109
    }
  }
}

// --------------------------------------------------------------- k_prepw1 ---
// W1b[o][k], k = cch*64 + dy*8 + dx  (dy,dx in 0..6 real, slot 7 zero)
__global__ void k_prepw1(const float* __restrict__ W1, uint16_t* __restrict__ W1b)
{
  int idx = blockIdx.x*256 + threadIdx.x;   // 64 blocks -> 16384
  int o = idx >> 7, kk = idx & 127;
  int cch = kk >> 6, r = kk & 63, dy = r >> 3, dx = r & 7;
  float v = (dy < 7 && dx < 7) ? W1[o*98 + cch*49 + dy*7 + dx] : 0.f;
  W1b[idx] = f2b(v);
}

// ---------------------------------------------------------------- k_fmapt ---
// tiled transpose: 64 (yx) x 64 (o) tiles; grid (22, 4)
__global__ void k_fmapt(const float* __restrict__ fmap, float* __restrict__ fmt){
  __shared__ float tile[64][65];
  int yx0 = blockIdx.x * 64;
  int o0  = blockIdx.y * 64;
  int tx = threadIdx.x & 63, ty = threadIdx.x >> 6;
  #pragma unroll
  for (int i=0;i<16;i++){
    int oo = ty*16 + i;
    int yx = yx0 + tx;
    tile[oo][tx] = (yx < 1369) ? fmap[(size_t)(o0+oo)*1369 + yx] : 0.f;
  }
  __syncthreads();
  #pragma unroll
  for (int i=0;i<16;i++){
    int r = ty*16 + i;
    int yx = yx0 + r;
    if (yx < 1369) fmt[(size_t)yx*256 + o0 + tx] = tile[tx][r];
  }
}

// ---------------------------------------------------------------- k_conv1 ---
// one block per pair, 512 threads. GEMM (o=128) x (m=256 pad, 196 real) x
// (k=128 pad, 98 real), operand-swapped: D rows = o, cols = m.
__global__ __launch_bounds__(512, 4) void k_conv1(
    const float* __restrict__ paird, const uint16_t* __restrict__ W1b,
    const float* __restrict__ b1v,
    uint16_t* __restrict__ p1, float* __restrict__ part1)
{
  __shared__ __align__(128) char lds[62976];
  uint16_t* smA  = (uint16_t*)lds;              // [256 m][72] per-64k chunk
  uint16_t* smB  = (uint16_t*)(lds + 36864);    // [128 o][72]
  uint16_t* smY  = (uint16_t*)lds;              // [196 m][132 o] epilogue (overlaps)
  float* cy0a = (float*)(lds + 55296);          // [14][8]
  float* cy1a = (float*)(lds + 55808);
  float* bya  = (float*)(lds + 56320);
  float* cx0a = (float*)(lds + 56832);
  float* cx1a = (float*)(lds + 57344);
  float* nbxa = (float*)(lds + 57856);
  float* smB1 = (float*)(lds + 58368);          // [128]
  float* smStat = (float*)(lds + 58880);        // [128][8]
  const int tid = threadIdx.x;
  const int n = blockIdx.x;
  const int wv = tid >> 6, lane = tid & 63, quad = lane >> 4, l15 = lane & 15;
  const float* pd = paird + (size_t)n*136;

  // phase 0: coverage lookup tables (slot dy/dx==7 -> 0)
  if (tid < 112){
    int Y = tid >> 3, dy = tid & 7;
    int yq = 2*Y + dy - 3;
    bool iy = (dy < 7) && ((unsigned)yq < 27u);
    int yqc = iy ? yq : 0;
    cy0a[tid] = iy ? pd[82+yqc]  : 0.f;
    cy1a[tid] = iy ? pd[109+yqc] : 0.f;
    bya[tid]  = iy ? 1.f : 0.f;
  } else if (tid >= 128 && tid < 240){
    int t2 = tid - 128;
    int X = t2 >> 3, dx = t2 & 7;
    int xq = 2*X + dx - 3;
    bool ix = (dx < 7) && ((unsigned)xq < 27u);
    int xqc = ix ? xq : 0;
    cx0a[t2] = ix ? pd[28+xqc] : 0.f;
    cx1a[t2] = ix ? pd[55+xqc] : 0.f;
    nbxa[t2] = ix ? -0.5f : 0.f;
  } else if (tid >= 256 && tid < 384){
    smB1[tid-256] = b1v[tid-256];
  }
  __syncthreads();

  const int m = tid & 255, h = tid >> 8;        // thread -> (A row, k-half)
  int Yr = m / 14, Xr = m - (m/14)*14;
  bool mv = (m < 196);
  int Yc = mv ? Yr : 0, Xc = mv ? Xr : 0;
  float byr[4], nbr[8];
  #pragma unroll
  for (int j=0;j<4;j++) byr[j] = mv ? bya[Yc*8 + h*4 + j] : 0.f;
  #pragma unroll
  for (int d=0;d<8;d++) nbr[d] = mv ? nbxa[Xc*8 + d] : 0.f;

  f32x4 zero4 = {0.f,0.f,0.f,0.f};
  f32x4 acc[8][2];
  #pragma unroll
  for (int io=0;io<8;io++){ acc[io][0] = zero4; acc[io][1] = zero4; }

  #pragma unroll
  for (int c=0;c<2;c++){
    // stage B chunk (bf16, already padded/ordered)
    {
      int o = tid >> 2, part = tid & 3;
      const uint4* src = (const uint4*)(W1b + o*128 + c*64);
      uint4* dst = (uint4*)(smB + o*72);
      dst[part*2]   = src[part*2];
      dst[part*2+1] = src[part*2+1];
    }
    // generate A chunk: k-local = dy*8+dx; per g, dy = h*4+g fixed
    {
      const float* cya = c ? cy1a : cy0a;
      const float* cxa = c ? cx1a : cx0a;
      float cyr[4], cxr[8];
      #pragma unroll
      for (int j=0;j<4;j++) cyr[j] = mv ? cya[Yc*8 + h*4 + j] : 0.f;
      #pragma unroll
      for (int d=0;d<8;d++) cxr[d] = mv ? cxa[Xc*8 + d] : 0.f;
      uint16_t* rowp = smA + m*72 + h*32;
      #pragma unroll
      for (int g=0; g<4; g++){
        uint32_t w[4];
        #pragma unroll
        for (int q=0; q<4; q++){
          float v0 = fmaf(cyr[g], cxr[q*2],   byr[g]*nbr[q*2]);
          float v1 = fmaf(cyr[g], cxr[q*2+1], byr[g]*nbr[q*2+1]);
          w[q] = pk2(v0, v1);
        }
        *(uint4*)(rowp + g*8) = make_uint4(w[0],w[1],w[2],w[3]);
      }
    }
    __syncthreads();
    #pragma unroll
    for (int ks=0; ks<2; ks++){
      bf16x8 rf0 = *(const bf16x8*)(smA + (wv*32      + l15)*72 + ks*32 + quad*8);
      bf16x8 rf1 = *(const bf16x8*)(smA + (wv*32 + 16 + l15)*72 + ks*32 + quad*8);
      #pragma unroll
      for (int io=0;io<8;io++){
        bf16x8 wf = *(const bf16x8*)(smB + (io*16 + l15)*72 + ks*32 + quad*8);
        acc[io][0] = mfma16(wf, rf0, acc[io][0]);
        acc[io][1] = mfma16(wf, rf1, acc[io][1]);
      }
    }
    __syncthreads();
  }

  // epilogue: y[m][o] = relu(acc + b1) -> smY, packed b64 writes
  #pragma unroll
  for (int io=0;io<8;io++){
    f32x4 bs = *(const f32x4*)(smB1 + io*16 + quad*4);
    #pragma unroll
    for (int jm=0;jm<2;jm++){
      int mm = wv*32 + jm*16 + l15;
      if (mm < 196){
        float v0 = fmaxf(acc[io][jm][0] + bs[0], 0.f);
        float v1 = fmaxf(acc[io][jm][1] + bs[1], 0.f);
        float v2 = fmaxf(acc[io][jm][2] + bs[2], 0.f);
        float v3 = fmaxf(acc[io][jm][3] + bs[3], 0.f);
        uint32_t w0 = pk2(v0,v1) & 0x7fff7fffu;   // clear -0 signs (u16 max safe)
        uint32_t w1 = pk2(v2,v3) & 0x7fff7fffu;
        *(uint2*)(smY + mm*132 + io*16 + quad*4) = make_uint2(w0, w1);
      }
    }
  }
  __syncthreads();

  // per-channel stats partials over 196 positions — b64 reads, 128 threads
  if (tid < 128){
    int oq = (tid & 31) * 4, hh = tid >> 5;     // 32 ch-quads x 4 row-groups
    float S0=0.f,S1=0.f,S2=0.f,S3=0.f,Q0=0.f,Q1=0.f,Q2=0.f,Q3=0.f;
    for (int r = hh*49; r < hh*49 + 49; r++){
      u16x4 v = *(const u16x4*)(smY + r*132 + oq);
      float f0 = b2f(v[0]), f1 = b2f(v[1]), f2 = b2f(v[2]), f3 = b2f(v[3]);
      S0 += f0; Q0 += f0*f0;
      S1 += f1; Q1 += f1*f1;
      S2 += f2; Q2 += f2*f2;
      S3 += f3; Q3 += f3*f3;
    }
    smStat[(oq+0)*8 + hh*2 + 0] = S0; smStat[(oq+0)*8 + hh*2 + 1] = Q0;
    smStat[(oq+1)*8 + hh*2 + 0] = S1; smStat[(oq+1)*8 + hh*2 + 1] = Q1;
    smStat[(oq+2)*8 + hh*2 + 0] = S2; smStat[(oq+2)*8 + hh*2 + 1] = Q2;
    smStat[(oq+3)*8 + hh*2 + 0] = S3; smStat[(oq+3)*8 + hh*2 + 1] = Q3;
  }

  // maxpool 3x3 s2 via packed u16x4 integer max (values >= 0, signs cleared)
  #pragma unroll
  for (int it=0; it<4; it++){
    int idx = tid + it*512;
    if (idx < 1568){                            // 49 pos x 32 ch-quads
      int pos = idx >> 5, oq = (idx & 31)*4;
      int Yp = pos / 7, Xp = pos - Yp*7;
      int yb = 2*Yp - 1, xb = 2*Xp - 1;
      u16x4 mx = {0,0,0,0};
      #pragma unroll
      for (int a=0;a<3;a++){
        int yy = yb + a;
        if ((unsigned)yy < 14u){
          #pragma unroll
          for (int b=0;b<3;b++){
            int xx = xb + b;
            if ((unsigned)xx < 14u){
              u16x4 v = *(const u16x4*)(smY + (yy*14+xx)*132 + oq);
#if defined(__has_builtin) && __has_builtin(__builtin_elementwise_max)
              mx = __builtin_elementwise_max(mx, v);
#else
              mx[0] = mx[0] > v[0] ? mx[0] : v[0];
              mx[1] = mx[1] > v[1] ? mx[1] : v[1];
              mx[2] = mx[2] > v[2] ? mx[2] : v[2];
              mx[3] = mx[3] > v[3] ? mx[3] : v[3];
#endif
            }
          }
        }
      }
      *(uint2*)(p1 + ((size_t)n*49 + pos)*128 + oq) = *(uint2*)&mx;
    }
  }
  __syncthreads();
  if (tid < 128){
    float S = smStat[tid*8+0] + smStat[tid*8+2] + smStat[tid*8+4] + smStat[tid*8+6];
    float Q = smStat[tid*8+1] + smStat[tid*8+3] + smStat[tid*8+5] + smStat[tid*8+7];
    part1[((size_t)n*128 + tid)*2 + 0] = S;
    part1[((size_t)n*128 + tid)*2 + 1] = Q;
  }
}

// --------------------------------------------------------------- k_stats1 ---
__global__ void k_stats1(const float* __restrict__ part1, const float* __restrict__ g1,
                         const float* __restrict__ be1, float* __restrict__ ab1)
{
  __shared__ float sS[256], sQ[256];
  int ch = blockIdx.x, t = threadIdx.x;
  float S=0.f, Q=0.f;
  for (int i=t; i<4096; i+=256){
    S += part1[((size_t)i*128 + ch)*2 + 0];
    Q += part1[((size_t)i*128 + ch)*2 + 1];
  }
  sS[t]=S; sQ[t]=Q;
  __syncthreads();
  for (int s=128; s>0; s>>=1){
    if (t < s){ sS[t]+=sS[t+s]; sQ[t]+=sQ[t+s]; }
    __syncthreads();
  }
  if (t==0){
    float N = 4096.0f*196.0f;
    float mean = sS[0]/N;
    float var = sQ[0]/N - mean*mean;
    float a = g1[ch] * rsqrtf(var + 1e-5f);
    ab1[ch*2+0] = a;
    ab1[ch*2+1] = be1[ch] - mean*a;
  }
}

// --------------------------------------------------------------- k_prepb2 ---
__global__ void k_prepb2(const float* __restrict__ W2, const float* __restrict__ b2v,
                         const float* __restrict__ ab1,
                         uint16_t* __restrict__ W2s, uint16_t* __restrict__ T2t)
{
  __shared__ float sA[128], sC[128], sU[9];
  int o = blockIdx.x, t = threadIdx.x;
  if (t < 128){ sA[t] = ab1[t*2+0]; sC[t] = ab1[t*2+1]; }
  __syncthreads();
  const float* w = W2 + (size_t)o*1152;
  for (int k=t; k<1152; k+=256){
    int c = k & 127, tap = k >> 7;
    W2s[(size_t)o*1152 + k] = f2b(w[c*9 + tap] * sA[c]);
  }
  if (t < 9){
    float u = 0.f;
    for (int c=0;c<128;c++) u += sC[c] * w[c*9 + t];
    sU[t] = u;
  }
  __syncthreads();
  if (t < 49){
    int y = t / 7, x = t - (t/7)*7;
    float s = b2v[o];
    #pragma unroll
    for (int dy=0;dy<3;dy++)
      #pragma unroll
      for (int dx=0;dx<3;dx++){
        int yy = y+dy-1, xx = x+dx-1;
        if ((unsigned)yy < 7u && (unsigned)xx < 7u) s += sU[dy*3+dx];
      }
    T2t[t*256 + o] = f2b(s);
  }
}

// ---------------------------------------------------------------- k_conv2 ---
// implicit GEMM: M=200704, N=256, K=1152 in 36 steps of BK=32.
// R8: 128x128 tiles, grid 3136 = 1568 m-tiles x 2 n-halves. acc[4][4] = 64
// AGPR -> total regs <=170 -> 3 blocks/CU (launch_bounds(256,3)).
// TRIPLE buffer (3 x 16KB), ONE barrier per step, counted vmcnt(4)
// (4 gld16/stage: 2 A + 2 B per wave); frag reads for s+1 interleaved into
// dead regs under MFMA(s). Both n-halves of an m-tile share an XCD.
// Swizzle (both sides, involution): within each 16-row x 64B group (1KB),
// logical (row r, 16B-chunk c) lives at physical slot p = (r>>1)*8 + cc',
// cc' = (c + 4*(r&1)) ^ ((r>>1)&7); staging decodes (r,c) from p=lane.
__global__ __launch_bounds__(256, 3) void k_conv2(
    const uint16_t* __restrict__ p1, const uint16_t* __restrict__ W2s,
    const uint16_t* __restrict__ T2t, const float* __restrict__ zpf,
    uint16_t* __restrict__ zplus, float* __restrict__ part2)
{
  __shared__ __align__(128) char lds[49152];   // 3 x (A 8KB + B 8KB)
  const int tid = threadIdx.x;
  const int bid = blockIdx.x;                  // bid = mt*2 + nt
  const int mt  = bid >> 1, nt = bid & 1;
  const int mswz = (mt & 7) * 196 + (mt >> 3); // XCD-bijective (1568%8==0)
  const int m0 = mswz * 128;
  const int n0 = nt << 7;
  const int wv = tid >> 6, lane = tid & 63, quad = lane >> 4, l15 = lane & 15;
  const int wm = wv >> 1, wn = wv & 1;

  // staging swizzle decode: physical slot 'lane' -> logical (row slr, chunk)
  const int sg   = lane >> 3;
  const int scc  = (lane & 7) ^ (sg & 7);
  const int slr  = (sg << 1) + (scc >> 2);
  const int coff = (scc & 3) << 4;

  const char* p1c = (const char*)p1;
  const char* w2c = (const char*)W2s;
  const char* zpc = (const char*)zpf;

  // A-row geometry for this lane's two staged rows (groups wv*2, wv*2+1)
  int abase0; unsigned amask = 0;
  {
    int mm0 = m0 + (wv << 5) + slr;
    abase0 = (mm0 << 8) + coff;
    #pragma unroll
    for (int i=0;i<2;i++){
      int mm = mm0 + (i << 4);
      int nn = mm / 49;
      int pp = mm - nn*49;
      int yy = pp / 7;
      int xx = pp - yy*7;
      unsigned mk = 0;
      #pragma unroll
      for (int dy=0; dy<3; dy++)
        #pragma unroll
        for (int dx=0; dx<3; dx++){
          int y2 = yy + dy - 1, x2 = xx + dx - 1;
          if ((unsigned)y2 < 7u && (unsigned)x2 < 7u) mk |= 1u << (dy*3+dx);
        }
      amask |= mk << (i*9);
    }
  }
  // B source offsets (rows n0 + wv*32 + i*16 + slr), row stride 2304 B
  int bbase[2];
  #pragma unroll
  for (int i=0;i<2;i++) bbase[i] = (n0 + (wv<<5) + (i<<4) + slr)*2304 + coff;

  // fragment read offsets (swizzled); +16 rows => +1024B (via (row>>4)<<10)
  int offA[2], offB[2];
  #pragma unroll
  for (int ia=0; ia<2; ia++){
    int row = wm*64 + ia*16 + l15;
    offA[ia] = ((row>>4)<<10) + (((row>>1)&7)<<7)
             + (((quad + ((row&1)<<2)) ^ ((row>>1)&7)) << 4);
  }
  #pragma unroll
  for (int jb=0; jb<2; jb++){
    int row = wn*64 + jb*16 + l15;
    offB[jb] = 8192 + ((row>>4)<<10) + (((row>>1)&7)<<7)
             + (((quad + ((row&1)<<2)) ^ ((row>>1)&7)) << 4);
  }

  auto stage = [&](int s, char* dst){
    int tap = s >> 2;                          // 0..8 (uniform)
    int dy = tap / 3, dx = tap - dy*3;
    int tdelta = (((dy-1)*7 + (dx-1)) << 8) + ((s & 3) << 6);
    const char* a0 = ((amask >> tap) & 1u)       ? (p1c + (abase0 + tdelta))
                                                 : (zpc + coff);
    const char* a1 = ((amask >> (tap + 9)) & 1u) ? (p1c + (abase0 + 4096 + tdelta))
                                                 : (zpc + coff);
    gld16(dst + ((wv*2+0)<<10), a0);
    gld16(dst + ((wv*2+1)<<10), a1);
    int bko = s << 6;
    gld16(dst + 8192 + ((wv*2+0)<<10), w2c + (bbase[0] + bko));
    gld16(dst + 8192 + ((wv*2+1)<<10), w2c + (bbase[1] + bko));
  };

  f32x4 zero4 = {0.f,0.f,0.f,0.f};
  f32x4 acc[4][4];
  #pragma unroll
  for (int ia=0;ia<4;ia++)
    #pragma unroll
    for (int jb=0;jb<4;jb++) acc[ia][jb] = zero4;

  // prologue: stage 0,1; wait stage0 landed; read frags(0)
  stage(0, lds);
  stage(1, lds + 16384);
  asm volatile("s_waitcnt vmcnt(4)" ::: "memory");
  __builtin_amdgcn_s_barrier();
  __builtin_amdgcn_sched_barrier(0);

  bf16x8 af[4], bb[4];
  #pragma unroll
  for (int ia=0;ia<4;ia++)
    af[ia] = *(const bf16x8*)(lds + (offA[ia&1] + ((ia>>1)<<11)));
  #pragma unroll
  for (int jb=0;jb<4;jb++)
    bb[jb] = *(const bf16x8*)(lds + (offB[jb&1] + ((jb>>1)<<11)));

  int c1 = 1, c2 = 2;                          // (s+1)%3, (s+2)%3
  for (int s=0; s<36; s++){
    if (s < 34) stage(s+2, lds + c2*16384);
    if (s < 35){
      if (s < 34) asm volatile("s_waitcnt vmcnt(4) lgkmcnt(0)" ::: "memory");
      else        asm volatile("s_waitcnt vmcnt(0) lgkmcnt(0)" ::: "memory");
      __builtin_amdgcn_s_barrier();
      __builtin_amdgcn_sched_barrier(0);
    }
    const char* nb = lds + c1*16384;
    __builtin_amdgcn_s_setprio(1);
    if (s < 35){
      #pragma unroll
      for (int jb=0;jb<4;jb++){
        #pragma unroll
        for (int ia=0;ia<4;ia++){
          acc[ia][jb] = mfma16(af[ia], bb[jb], acc[ia][jb]);
          if (jb == 3)                         // af[ia] dead after last group
            af[ia] = *(const bf16x8*)(nb + (offA[ia&1] + ((ia>>1)<<11)));
        }
        bb[jb] = *(const bf16x8*)(nb + (offB[jb&1] + ((jb>>1)<<11)));
      }
    } else {
      #pragma unroll
      for (int jb=0;jb<4;jb++)
        #pragma unroll
        for (int ia=0;ia<4;ia++)
          acc[ia][jb] = mfma16(af[ia], bb[jb], acc[ia][jb]);
    }
    __builtin_amdgcn_s_setprio(0);
    c1 = (c1 == 2) ? 0 : c1 + 1;
    c2 = (c2 == 2) ? 0 : c2 + 1;
  }
  __syncthreads();   // drain + sync before repurposing LDS (no gld16 pending)

  // ---- epilogue: bias+relu -> bf16, transpose via LDS in 4 quarters of 32 m
  uint16_t* smT = (uint16_t*)(lds + 16384);     // [49][128] bias half (12.25KB)
  #pragma unroll
  for (int i=0;i<4;i++){
    int idx = tid + i*256;
    if (idx < 784){                             // 49 rows x 16 uint4
      int pos = idx >> 4, c8 = idx & 15;
      ((uint4*)smT)[idx] = *((const uint4*)(T2t + pos*256 + n0) + c8);
    }
  }
  uint16_t* smZ = (uint16_t*)lds;               // [32][128] quarter buffer (8KB)
  float S = 0.f, Q = 0.f;
  const int cl = tid & 127, hh = tid >> 7;
  #pragma unroll
  for (int q=0; q<4; q++){
    __syncthreads();
    if (wm == (q>>1)){
      #pragma unroll
      for (int t2=0;t2<2;t2++){
        int ia = ((q&1)<<1) + t2;
        #pragma unroll
        for (int reg=0; reg<4; reg++){
          int rl = t2*16 + quad*4 + reg;        // row within quarter
          int mm = m0 + q*32 + rl;
          int pos = mm % 49;
          const uint16_t* tr = smT + pos*128;
          uint16_t* zr = smZ + rl*128;
          #pragma unroll
          for (int jb=0;jb<4;jb++){
            int col = wn*64 + jb*16 + l15;
            float z = acc[ia][jb][reg] + b2f(tr[col]);
            zr[col] = f2b(fmaxf(z, 0.0f));
          }
        }
      }
    }
    __syncthreads();
    #pragma unroll
    for (int i2=0;i2<2;i2++){
      int idx = tid + i2*256;                   // 512 uint4 = 8KB
      int row = idx >> 4, off = idx & 15;
      *(uint4*)(zplus + ((size_t)(m0 + q*32 + row))*256 + n0 + off*8)
          = ((const uint4*)smZ)[idx];
    }
    for (int r = hh*16; r < hh*16 + 16; r++){
      float v = b2f(smZ[r*128 + cl]);
      S += v; Q += v*v;
    }
  }
  // reduce the two hh partials so part2 keeps its [1568][256][2] layout
  __syncthreads();
  float* sred = (float*)lds;                    // 128 x 2 floats
  if (tid >= 128){ sred[cl*2+0] = S; sred[cl*2+1] = Q; }
  __syncthreads();
  if (tid < 128){
    S += sred[tid*2+0]; Q += sred[tid*2+1];
    part2[((size_t)mswz*256 + n0 + tid)*2 + 0] = S;
    part2[((size_t)mswz*256 + n0 + tid)*2 + 1] = Q;
  }
}

// --------------------------------------------------------------- k_stats2 ---
__global__ void k_stats2(const float* __restrict__ part2, const float* __restrict__ g2,
                         const float* __restrict__ be2, float* __restrict__ ab2)
{
  __shared__ float sS[256], sQ[256];
  int ch = blockIdx.x, t = threadIdx.x;
  float S=0.f, Q=0.f;
  for (int i=t; i<1568; i+=256){
    S += part2[((size_t)i*256 + ch)*2 + 0];
    Q += part2[((size_t)i*256 + ch)*2 + 1];
  }
  sS[t]=S; sQ[t]=Q;
  __syncthreads();
  for (int s=128; s>0; s>>=1){
    if (t < s){ sS[t]+=sS[t+s]; sQ[t]+=sQ[t+s]; }
    __syncthreads();
  }
  if (t==0){
    float N = 200704.0f;
    float mean = sS[0]/N;
    float var = sQ[0]/N - mean*mean;
    float a = g2[ch] * rsqrtf(var + 1e-5f);
    ab2[ch*2+0] = a;
    ab2[ch*2+1] = be2[ch] - mean*a;
  }
}

// ---------------------------------------------------------------- k_final ---
__global__ __launch_bounds__(256) void k_final(
    const float* __restrict__ paird, const float* __restrict__ fmt,
    const uint16_t* __restrict__ zplus, const float* __restrict__ ab2,
    float* __restrict__ out)
{
  __shared__ float smRes[12544];     // [o][pos] transpose buffer
  __shared__ int   smTI[196];
  __shared__ float smTW[196];
  int n = blockIdx.x, tid = threadIdx.x;
  if (tid < 49){
    const float* pd = paird + (size_t)n*136;
    int py = tid / 7, px = tid - (tid/7)*7;
    float x0 = pd[px],    wx = pd[7+px];
    float y0 = pd[14+py], wy = pd[21+py];
    int x0i = (int)x0, y0i = (int)y0;
    int x1i = min(x0i+1, 36), y1i = min(y0i+1, 36);
    smTI[tid*4+0] = (y0i*37+x0i)*256;
    smTI[tid*4+1] = (y0i*37+x1i)*256;
    smTI[tid*4+2] = (y1i*37+x0i)*256;
    smTI[tid*4+3] = (y1i*37+x1i)*256;
    smTW[tid*4+0] = (1.f-wy)*(1.f-wx);
    smTW[tid*4+1] = (1.f-wy)*wx;
    smTW[tid*4+2] = wy*(1.f-wx);
    smTW[tid*4+3] = wy*wx;
  }
  float a2 = ab2[tid*2+0], c2 = ab2[tid*2+1];   // tid == channel o
  __syncthreads();
  const uint16_t* zrow = zplus + (size_t)n*49*256 + tid;
  int o = tid;
  for (int pos=0; pos<49; pos++){
    float v = smTW[pos*4+0]*fmt[smTI[pos*4+0]+o]
            + smTW[pos*4+1]*fmt[smTI[pos*4+1]+o]
            + smTW[pos*4+2]*fmt[smTI[pos*4+2]+o]
            + smTW[pos*4+3]*fmt[smTI[pos*4+3]+o];
    float z = b2f(zrow[(size_t)pos*256]);
    smRes[o*49 + pos] = v + a2*z + c2;
  }
  __syncthreads();
  float* op = out + (size_t)n*12544;
  #pragma unroll
  for (int i=0;i<13;i++){
    int idx = tid + i*256;                      // 3136 float4 = 12544 floats
    if (idx < 3136)
      ((float4*)op)[idx] = ((const float4*)smRes)[idx];
  }
}

// ----------------------------------------------------------- kernel_launch --
extern "C" void kernel_launch(void* const* d_in, const int* in_sizes, int n_in,
                              void* d_out, int out_size, void* d_ws, size_t ws_size,
                              hipStream_t stream)
{
  const float* fmap = (const float*)d_in[0];
  const float* rois = (const float*)d_in[1];
  const int*   ui   = (const int*)d_in[2];
  const float* W1   = (const float*)d_in[3];
  const float* b1   = (const float*)d_in[4];
  const float* g1   = (const float*)d_in[5];
  const float* be1  = (const float*)d_in[6];
  const float* W2   = (const float*)d_in[7];
  const float* b2   = (const float*)d_in[8];
  const float* g2   = (const float*)d_in[9];
  const float* be2  = (const float*)d_in[10];
  float* out = (float*)d_out;
  char* ws = (char*)d_ws;

  constexpr size_t OFF_ZERO = 0;                             // 256 B zero page
  constexpr size_t OFF_PAIR = 256;                           // 4096*136*4
  constexpr size_t OFF_FMT  = OFF_PAIR + 4096u*136*4;        // 350464*4
  constexpr size_t OFF_W1B  = OFF_FMT + 350464u*4;           // 16384*2
  constexpr size_t OFF_P1   = OFF_W1B + 16384u*2;            // 200704*128*2
  constexpr size_t OFF_ZP   = OFF_P1 + (size_t)200704*128*2; // 200704*256*2
  constexpr size_t OFF_W2S  = OFF_ZP + (size_t)200704*256*2; // 294912*2
  constexpr size_t OFF_T2   = OFF_W2S + 294912u*2;           // 12544*2
  constexpr size_t OFF_S1   = OFF_T2 + 12544u*2;             // 4096*128*2*4
  constexpr size_t OFF_AB1  = OFF_S1 + 4096u*128*2*4;        // 128*2*4
  constexpr size_t OFF_S2   = OFF_AB1 + 1024;                // 1568*256*2*4
  constexpr size_t OFF_AB2  = OFF_S2 + 1568u*256*2*4;        // 256*2*4

  float*    zp    = (float*)(ws + OFF_ZERO);
  float*    pair  = (float*)(ws + OFF_PAIR);
  float*    fmt   = (float*)(ws + OFF_FMT);
  uint16_t* W1b   = (uint16_t*)(ws + OFF_W1B);
  uint16_t* p1    = (uint16_t*)(ws + OFF_P1);
  uint16_t* zplus = (uint16_t*)(ws + OFF_ZP);
  uint16_t* W2s   = (uint16_t*)(ws + OFF_W2S);
  uint16_t* T2t   = (uint16_t*)(ws + OFF_T2);
  float*    part1 = (float*)(ws + OFF_S1);
  float*    ab1   = (float*)(ws + OFF_AB1);
  float*    part2 = (float*)(ws + OFF_S2);
  float*    ab2   = (float*)(ws + OFF_AB2);

  k_setup <<<16,   256, 0, stream>>>(rois, ui, pair, zp);
  k_prepw1<<<64,   256, 0, stream>>>(W1, W1b);
  k_fmapt <<<dim3(22,4), 256, 0, stream>>>(fmap, fmt);
  k_conv1 <<<4096, 512, 0, stream>>>(pair, W1b, b1, p1, part1);
  k_stats1<<<128,  256, 0, stream>>>(part1, g1, be1, ab1);
  k_prepb2<<<256,  256, 0, stream>>>(W2, b2, ab1, W2s, T2t);
  k_conv2 <<<3136, 256, 0, stream>>>(p1, W2s, T2t, zp, zplus, part2);
  k_stats2<<<256,  256, 0, stream>>>(part2, g2, be2, ab2);
  k_final <<<4096, 256, 0, stream>>>(pair, fmt, zplus, ab2, out);
}